// Round 1
// baseline (859.880 us; speedup 1.0000x reference)
//
#include <hip/hip_runtime.h>
#include <hip/hip_bf16.h>

constexpr int BATCH = 256, NNODE = 512, WINW = 64, EMBD = 64, KTOP = 16, CIN = 512;
constexpr int NTOT = BATCH * NNODE;          // 131072
constexpr float NEGS = 0.2f;
constexpr float EPSBN = 1e-5f;

__device__ inline float bf2f(unsigned u16) {
  union { unsigned u; float f; } v; v.u = u16 << 16; return v.f;
}
__device__ inline unsigned short f2bf(float x) {
  union { float f; unsigned u; } v; v.f = x;
  unsigned r = v.u + 0x7fff + ((v.u >> 16) & 1);
  return (unsigned short)(r >> 16);
}

// ---- K0: normalize embeddings + per-node attention-embedding dots ----------
__global__ void k_prep(const float* __restrict__ W_emb,
                       const float* __restrict__ att_em_i,
                       const float* __restrict__ att_em_j,
                       float* __restrict__ nw, float* __restrict__ emb_si,
                       float* __restrict__ emb_sj) {
  int i = blockIdx.x, e = threadIdx.x;   // block = 64 threads
  float w  = W_emb[i * EMBD + e];
  float sq = w * w;
  float si = w * att_em_i[e];
  float sj = w * att_em_j[e];
  for (int o = 32; o > 0; o >>= 1) {
    sq += __shfl_xor(sq, o);
    si += __shfl_xor(si, o);
    sj += __shfl_xor(sj, o);
  }
  nw[i * EMBD + e] = w * rsqrtf(sq);
  if (e == 0) { emb_si[i] = si; emb_sj[i] = sj; }
}

// ---- K1: cosine top-16 per node (block per node row) -----------------------
__global__ __launch_bounds__(256) void k_topk(const float* __restrict__ nw,
                                              int* __restrict__ topk) {
  __shared__ float cosv[NNODE];
  __shared__ float nwi[EMBD];
  __shared__ float rv[256];
  __shared__ int   ri[256];
  int i = blockIdx.x, t = threadIdx.x;
  if (t < EMBD) nwi[t] = nw[i * EMBD + t];
  __syncthreads();
  for (int j = t; j < NNODE; j += 256) {
    float d = 0.f;
    #pragma unroll
    for (int k = 0; k < EMBD; k++) d += nw[j * EMBD + k] * nwi[k];
    cosv[j] = d;
  }
  __syncthreads();
  for (int sel = 0; sel < KTOP; sel++) {
    float v0 = cosv[t], v1 = cosv[t + 256];
    float bv = v0; int bi = t;
    if (v1 > v0) { bv = v1; bi = t + 256; }   // tie -> lower index (lax.top_k)
    rv[t] = bv; ri[t] = bi;
    __syncthreads();
    for (int s = 128; s > 0; s >>= 1) {
      if (t < s) {
        float ov = rv[t + s]; int oi = ri[t + s];
        if (ov > rv[t] || (ov == rv[t] && oi < ri[t])) { rv[t] = ov; ri[t] = oi; }
      }
      __syncthreads();
    }
    if (t == 0) { topk[i * KTOP + sel] = ri[0]; cosv[ri[0]] = -2.f; }
    __syncthreads();
  }
}

// ---- K2: xl = x @ W_lin^T, per-node scores s_i, s_j ------------------------
__global__ __launch_bounds__(256) void k_lin(
    const float* __restrict__ data, const float* __restrict__ W_lin,
    const float* __restrict__ att_i, const float* __restrict__ att_j,
    const float* __restrict__ emb_si, const float* __restrict__ emb_sj,
    float* __restrict__ xl, float* __restrict__ s_i, float* __restrict__ s_j) {
  __shared__ float Wl[EMBD][EMBD + 1];   // +1 pad: 2-way bank alias only
  __shared__ float xs[4][WINW];
  int t = threadIdx.x, wv = t >> 6, ln = t & 63;
  for (int idx = t; idx < EMBD * WINW; idx += 256)
    Wl[idx >> 6][idx & 63] = W_lin[idx];
  float ai = att_i[ln], aj = att_j[ln];
  int rowbase = blockIdx.x * 64;   // 64 rows per block
  for (int it = 0; it < 16; it++) {
    int r0 = rowbase + it * 4;
    __syncthreads();
    xs[t >> 6][t & 63] = data[(r0 + (t >> 6)) * WINW + (t & 63)];
    __syncthreads();
    int n = r0 + wv;
    float acc = 0.f;
    #pragma unroll
    for (int k = 0; k < WINW; k++) acc += xs[wv][k] * Wl[ln][k];
    xl[n * EMBD + ln] = acc;
    float pi = acc * ai, pj = acc * aj;
    for (int o = 32; o > 0; o >>= 1) { pi += __shfl_xor(pi, o); pj += __shfl_xor(pj, o); }
    if (ln == 0) {
      int node = n & (NNODE - 1);
      s_i[n] = pi + emb_si[node];
      s_j[n] = pj + emb_sj[node];
    }
  }
}

// ---- K3: edge softmax + aggregation + BN1 stats ----------------------------
__global__ __launch_bounds__(256) void k_edges(
    const float* __restrict__ xl, const float* __restrict__ s_i,
    const float* __restrict__ s_j, const int* __restrict__ topk,
    float* __restrict__ agg, float* __restrict__ gsum1, float* __restrict__ gss1) {
  int t = threadIdx.x, wv = t >> 6, ln = t & 63;
  __shared__ float red[2][4][64];
  float ps = 0.f, pss = 0.f;
  int base = blockIdx.x * 128;          // 128 nodes/block, grid 1024
  for (int it = 0; it < 32; it++) {
    int n = base + it * 4 + wv;         // wave-uniform dst node
    int node = n & (NNODE - 1);
    int boff = n - node;
    float sin = s_i[n];
    float al[KTOP]; int sr[KTOP];
    float m = -1e30f;
    #pragma unroll
    for (int k = 0; k < KTOP; k++) {
      int s = topk[node * KTOP + k] + boff;
      sr[k] = s;
      float a = sin + s_j[s];
      a = a > 0.f ? a : NEGS * a;       // leaky_relu
      al[k] = a;
      m = fmaxf(m, a);
    }
    float den = 0.f;
    #pragma unroll
    for (int k = 0; k < KTOP; k++) { al[k] = __expf(al[k] - m); den += al[k]; }
    float inv = 1.f / den;
    float a = 0.f;
    #pragma unroll
    for (int k = 0; k < KTOP; k++) a += al[k] * xl[sr[k] * EMBD + ln];
    a *= inv;
    agg[n * EMBD + ln] = a;
    ps += a; pss += a * a;
  }
  red[0][wv][ln] = ps; red[1][wv][ln] = pss;
  __syncthreads();
  if (t < 64) {
    atomicAdd(&gsum1[t], red[0][0][t] + red[0][1][t] + red[0][2][t] + red[0][3][t]);
  } else if (t < 128) {
    int e = t - 64;
    atomicAdd(&gss1[e], red[1][0][e] + red[1][1][e] + red[1][2][e] + red[1][3][e]);
  }
}

// ---- finalize BN coefficients: a = g*rsqrt(var+eps), c = b - mean*a --------
__global__ void k_fin(const float* __restrict__ gsum, const float* __restrict__ gss,
                      const float* __restrict__ g, const float* __restrict__ bb,
                      float* __restrict__ a, float* __restrict__ c, int C) {
  int e = blockIdx.x * blockDim.x + threadIdx.x;
  if (e >= C) return;
  const float invn = 1.f / (float)NTOT;
  float m = gsum[e] * invn;
  float v = gss[e] * invn - m * m;
  float aa = g[e] * rsqrtf(v + EPSBN);
  a[e] = aa;
  c[e] = bb[e] - m * aa;
}

// ---- K5: z = relu(bn1(agg)) * W_emb, BN2 stats -----------------------------
// (b_gnn cancels exactly inside training-mode BN: shift-invariant)
__global__ __launch_bounds__(256) void k_z(
    const float* __restrict__ agg, const float* __restrict__ W_emb,
    const float* __restrict__ a1, const float* __restrict__ c1,
    float* __restrict__ z, float* __restrict__ gsum2, float* __restrict__ gss2) {
  int t = threadIdx.x, wv = t >> 6, ln = t & 63;
  __shared__ float red[2][4][64];
  float aa = a1[ln], cc = c1[ln];
  float ps = 0.f, pss = 0.f;
  int stride = gridDim.x * 256;         // multiple of 64 -> channel fixed = ln
  for (int idx = blockIdx.x * 256 + t; idx < NTOT * EMBD; idx += stride) {
    int node = (idx >> 6) & (NNODE - 1);
    float h = agg[idx] * aa + cc;
    h = h > 0.f ? h : 0.f;
    float zz = h * W_emb[node * EMBD + ln];
    z[idx] = zz;
    ps += zz; pss += zz * zz;
  }
  red[0][wv][ln] = ps; red[1][wv][ln] = pss;
  __syncthreads();
  if (t < 64) {
    atomicAdd(&gsum2[t], red[0][0][t] + red[0][1][t] + red[0][2][t] + red[0][3][t]);
  } else if (t < 128) {
    int e = t - 64;
    atomicAdd(&gss2[e], red[1][0][e] + red[1][1][e] + red[1][2][e] + red[1][3][e]);
  }
}

// ---- K7: z2 = relu(bn2(z)) @ W1^T + b1, stored bf16 ------------------------
// thread per row; W1/b1/a2/c2 reads are wave-uniform -> scalar loads
__global__ __launch_bounds__(256) void k_gemm(
    const float* __restrict__ z, const float* __restrict__ W1,
    const float* __restrict__ b1, const float* __restrict__ a2,
    const float* __restrict__ c2, unsigned short* __restrict__ z2) {
  int n = blockIdx.x * 256 + threadIdx.x;
  float h[EMBD];
  const float4* zr = (const float4*)(z + (size_t)n * EMBD);
  #pragma unroll
  for (int q = 0; q < EMBD / 4; q++) {
    float4 v = zr[q];
    float h0 = v.x * a2[4 * q + 0] + c2[4 * q + 0];
    float h1 = v.y * a2[4 * q + 1] + c2[4 * q + 1];
    float h2 = v.z * a2[4 * q + 2] + c2[4 * q + 2];
    float h3 = v.w * a2[4 * q + 3] + c2[4 * q + 3];
    h[4 * q + 0] = h0 > 0.f ? h0 : 0.f;
    h[4 * q + 1] = h1 > 0.f ? h1 : 0.f;
    h[4 * q + 2] = h2 > 0.f ? h2 : 0.f;
    h[4 * q + 3] = h3 > 0.f ? h3 : 0.f;
  }
  unsigned short* orow = z2 + (size_t)n * CIN;
  for (int c0 = 0; c0 < CIN; c0 += 8) {
    float acc[8];
    #pragma unroll
    for (int j = 0; j < 8; j++) acc[j] = b1[c0 + j];
    #pragma unroll 8
    for (int k = 0; k < EMBD; k++) {
      float hv = h[k];
      #pragma unroll
      for (int j = 0; j < 8; j++) acc[j] += hv * W1[(c0 + j) * EMBD + k];
    }
    uint4 pk;
    pk.x = (unsigned)f2bf(acc[0]) | ((unsigned)f2bf(acc[1]) << 16);
    pk.y = (unsigned)f2bf(acc[2]) | ((unsigned)f2bf(acc[3]) << 16);
    pk.z = (unsigned)f2bf(acc[4]) | ((unsigned)f2bf(acc[5]) << 16);
    pk.w = (unsigned)f2bf(acc[6]) | ((unsigned)f2bf(acc[7]) << 16);
    *(uint4*)(orow + c0) = pk;
  }
}

// ---- K8: BN3 stats over z2 (coalesced uint reads, 2 channels/thread) -------
__global__ __launch_bounds__(256) void k_stats3(
    const unsigned* __restrict__ z2p, float* __restrict__ gsum3,
    float* __restrict__ gss3) {
  int gtid = blockIdx.x * 256 + threadIdx.x;
  int stride = gridDim.x * 256;              // 262144, multiple of 256 pairs
  int c0 = (2 * gtid) & (CIN - 1);           // fixed channel pair per thread
  float ps0 = 0.f, pss0 = 0.f, ps1 = 0.f, pss1 = 0.f;
  const int total2 = NTOT * CIN / 2;
  for (int idx = gtid; idx < total2; idx += stride) {
    unsigned u = z2p[idx];
    float v0 = bf2f(u & 0xffffu);
    float v1 = bf2f(u >> 16);
    ps0 += v0; pss0 += v0 * v0;
    ps1 += v1; pss1 += v1 * v1;
  }
  atomicAdd(&gsum3[c0], ps0);
  atomicAdd(&gss3[c0], pss0);
  atomicAdd(&gsum3[c0 + 1], ps1);
  atomicAdd(&gss3[c0 + 1], pss1);
}

// ---- K9: out = relu(bn3(z2)) @ W2^T + b2 -----------------------------------
__global__ __launch_bounds__(256) void k_out(
    const unsigned short* __restrict__ z2, const float* __restrict__ a3,
    const float* __restrict__ c3, const float* __restrict__ W2,
    const float* __restrict__ b2, float* __restrict__ out) {
  __shared__ float sa[CIN], sc[CIN], sw[CIN];
  int t = threadIdx.x, wv = t >> 6, ln = t & 63;
  for (int i = t; i < CIN; i += 256) { sa[i] = a3[i]; sc[i] = c3[i]; sw[i] = W2[i]; }
  __syncthreads();
  float bb = b2[0];
  int base = blockIdx.x * 64;   // 64 rows per block, grid 2048
  for (int it = 0; it < 16; it++) {
    int n = base + it * 4 + wv;
    const unsigned* row = (const unsigned*)(z2 + (size_t)n * CIN);
    float acc = 0.f;
    #pragma unroll
    for (int j = 0; j < 4; j++) {
      unsigned u = row[ln + 64 * j];
      int c = 2 * (ln + 64 * j);
      float v0 = bf2f(u & 0xffffu);
      float v1 = bf2f(u >> 16);
      float x0 = sa[c] * v0 + sc[c];       x0 = x0 > 0.f ? x0 : 0.f;
      float x1 = sa[c + 1] * v1 + sc[c + 1]; x1 = x1 > 0.f ? x1 : 0.f;
      acc += sw[c] * x0 + sw[c + 1] * x1;
    }
    for (int o = 32; o > 0; o >>= 1) acc += __shfl_xor(acc, o);
    if (ln == 0) out[n] = acc + bb;
  }
}

extern "C" void kernel_launch(void* const* d_in, const int* in_sizes, int n_in,
                              void* d_out, int out_size, void* d_ws, size_t ws_size,
                              hipStream_t stream) {
  const float* data     = (const float*)d_in[0];
  // d_in[1] org_edge_index: unused by forward
  const float* W_emb    = (const float*)d_in[2];
  const float* W_lin    = (const float*)d_in[3];
  const float* att_i    = (const float*)d_in[4];
  const float* att_j    = (const float*)d_in[5];
  const float* att_em_i = (const float*)d_in[6];
  const float* att_em_j = (const float*)d_in[7];
  // d_in[8] b_gnn: cancels exactly inside training-mode BN1
  const float* g_bn1    = (const float*)d_in[9];
  const float* b_bn1    = (const float*)d_in[10];
  const float* g_bn2    = (const float*)d_in[11];
  const float* b_bn2    = (const float*)d_in[12];
  const float* W1       = (const float*)d_in[13];
  const float* b1       = (const float*)d_in[14];
  const float* g_bn3    = (const float*)d_in[15];
  const float* b_bn3    = (const float*)d_in[16];
  const float* W2       = (const float*)d_in[17];
  const float* b2       = (const float*)d_in[18];
  float* out = (float*)d_out;

  char* p = (char*)d_ws;
  auto alloc = [&](size_t bytes) {
    void* r = (void*)p;
    p += (bytes + 255) & ~(size_t)255;
    return r;
  };
  unsigned short* z2 = (unsigned short*)alloc((size_t)NTOT * CIN * 2); // 134 MB bf16
  float* xl   = (float*)alloc((size_t)NTOT * EMBD * 4);  // reused as z after k_edges
  float* agg  = (float*)alloc((size_t)NTOT * EMBD * 4);
  float* s_i  = (float*)alloc((size_t)NTOT * 4);
  float* s_j  = (float*)alloc((size_t)NTOT * 4);
  float* nw   = (float*)alloc((size_t)NNODE * EMBD * 4);
  float* emb_si = (float*)alloc(NNODE * 4);
  float* emb_sj = (float*)alloc(NNODE * 4);
  int*   topk   = (int*)alloc(NNODE * KTOP * 4);
  float* stats  = (float*)alloc((64 * 4 + 512 * 2) * 4);  // sums/sumsqs
  float* coefs  = (float*)alloc((64 * 4 + 512 * 2) * 4);  // a/c per BN

  float* gsum1 = stats;       float* gss1 = stats + 64;
  float* gsum2 = stats + 128; float* gss2 = stats + 192;
  float* gsum3 = stats + 256; float* gss3 = stats + 768;
  float* a1 = coefs;       float* c1 = coefs + 64;
  float* a2 = coefs + 128; float* c2 = coefs + 192;
  float* a3 = coefs + 256; float* c3 = coefs + 768;
  float* zbuf = xl;   // xl is dead after k_edges

  hipMemsetAsync(stats, 0, (64 * 4 + 512 * 2) * 4, stream);

  k_prep<<<NNODE, 64, 0, stream>>>(W_emb, att_em_i, att_em_j, nw, emb_si, emb_sj);
  k_topk<<<NNODE, 256, 0, stream>>>(nw, topk);
  k_lin<<<NTOT / 64, 256, 0, stream>>>(data, W_lin, att_i, att_j, emb_si, emb_sj,
                                       xl, s_i, s_j);
  k_edges<<<NTOT / 128, 256, 0, stream>>>(xl, s_i, s_j, topk, agg, gsum1, gss1);
  k_fin<<<1, 64, 0, stream>>>(gsum1, gss1, g_bn1, b_bn1, a1, c1, EMBD);
  k_z<<<1024, 256, 0, stream>>>(agg, W_emb, a1, c1, zbuf, gsum2, gss2);
  k_fin<<<1, 64, 0, stream>>>(gsum2, gss2, g_bn2, b_bn2, a2, c2, EMBD);
  k_gemm<<<NTOT / 256, 256, 0, stream>>>(zbuf, W1, b1, a2, c2, z2);
  k_stats3<<<1024, 256, 0, stream>>>((const unsigned*)z2, gsum3, gss3);
  k_fin<<<1, 512, 0, stream>>>(gsum3, gss3, g_bn3, b_bn3, a3, c3, CIN);
  k_out<<<NTOT / 64, 256, 0, stream>>>(z2, a3, c3, W2, b2, out);
}

// Round 2
// 430.285 us; speedup vs baseline: 1.9984x; 1.9984x over previous
//
#include <hip/hip_runtime.h>
#include <hip/hip_bf16.h>

constexpr int BATCH = 256, NNODE = 512, WINW = 64, EMBD = 64, KTOP = 16, CIN = 512;
constexpr int NTOT = BATCH * NNODE;          // 131072
constexpr float NEGS = 0.2f;
constexpr float EPSBN = 1e-5f;

typedef __attribute__((ext_vector_type(8))) short bf16x8;
typedef __attribute__((ext_vector_type(4))) float f32x4;

__device__ inline float bf2f(unsigned u16) {
  union { unsigned u; float f; } v; v.u = u16 << 16; return v.f;
}
__device__ inline unsigned short f2bf(float x) {
  union { float f; unsigned u; } v; v.f = x;
  unsigned r = v.u + 0x7fff + ((v.u >> 16) & 1);   // RNE
  return (unsigned short)(r >> 16);
}

// ---- K0: normalize embeddings + per-node attention-embedding dots ----------
__global__ void k_prep(const float* __restrict__ W_emb,
                       const float* __restrict__ att_em_i,
                       const float* __restrict__ att_em_j,
                       float* __restrict__ nw, float* __restrict__ emb_si,
                       float* __restrict__ emb_sj) {
  int i = blockIdx.x, e = threadIdx.x;   // block = 64 threads
  float w  = W_emb[i * EMBD + e];
  float sq = w * w;
  float si = w * att_em_i[e];
  float sj = w * att_em_j[e];
  for (int o = 32; o > 0; o >>= 1) {
    sq += __shfl_xor(sq, o);
    si += __shfl_xor(si, o);
    sj += __shfl_xor(sj, o);
  }
  nw[i * EMBD + e] = w * rsqrtf(sq);
  if (e == 0) { emb_si[i] = si; emb_sj[i] = sj; }
}

// ---- K1: cosine top-16 per node (block per node row) -----------------------
__global__ __launch_bounds__(256) void k_topk(const float* __restrict__ nw,
                                              int* __restrict__ topk) {
  __shared__ float cosv[NNODE];
  __shared__ float nwi[EMBD];
  __shared__ float rv[256];
  __shared__ int   ri[256];
  int i = blockIdx.x, t = threadIdx.x;
  if (t < EMBD) nwi[t] = nw[i * EMBD + t];
  __syncthreads();
  for (int j = t; j < NNODE; j += 256) {
    float d = 0.f;
    #pragma unroll
    for (int k = 0; k < EMBD; k++) d += nw[j * EMBD + k] * nwi[k];
    cosv[j] = d;
  }
  __syncthreads();
  for (int sel = 0; sel < KTOP; sel++) {
    float v0 = cosv[t], v1 = cosv[t + 256];
    float bv = v0; int bi = t;
    if (v1 > v0) { bv = v1; bi = t + 256; }   // tie -> lower index (lax.top_k)
    rv[t] = bv; ri[t] = bi;
    __syncthreads();
    for (int s = 128; s > 0; s >>= 1) {
      if (t < s) {
        float ov = rv[t + s]; int oi = ri[t + s];
        if (ov > rv[t] || (ov == rv[t] && oi < ri[t])) { rv[t] = ov; ri[t] = oi; }
      }
      __syncthreads();
    }
    if (t == 0) { topk[i * KTOP + sel] = ri[0]; cosv[ri[0]] = -2.f; }
    __syncthreads();
  }
}

// ---- K2: xl = x @ W_lin^T, per-node scores s_i, s_j ------------------------
__global__ __launch_bounds__(256) void k_lin(
    const float* __restrict__ data, const float* __restrict__ W_lin,
    const float* __restrict__ att_i, const float* __restrict__ att_j,
    const float* __restrict__ emb_si, const float* __restrict__ emb_sj,
    float* __restrict__ xl, float* __restrict__ s_i, float* __restrict__ s_j) {
  __shared__ float Wl[EMBD][EMBD + 1];
  __shared__ float xs[4][WINW];
  int t = threadIdx.x, wv = t >> 6, ln = t & 63;
  for (int idx = t; idx < EMBD * WINW; idx += 256)
    Wl[idx >> 6][idx & 63] = W_lin[idx];
  float ai = att_i[ln], aj = att_j[ln];
  int rowbase = blockIdx.x * 64;   // 64 rows per block
  for (int it = 0; it < 16; it++) {
    int r0 = rowbase + it * 4;
    __syncthreads();
    xs[t >> 6][t & 63] = data[(r0 + (t >> 6)) * WINW + (t & 63)];
    __syncthreads();
    int n = r0 + wv;
    float acc = 0.f;
    #pragma unroll
    for (int k = 0; k < WINW; k++) acc += xs[wv][k] * Wl[ln][k];
    xl[n * EMBD + ln] = acc;
    float pi = acc * ai, pj = acc * aj;
    for (int o = 32; o > 0; o >>= 1) { pi += __shfl_xor(pi, o); pj += __shfl_xor(pj, o); }
    if (ln == 0) {
      int node = n & (NNODE - 1);
      s_i[n] = pi + emb_si[node];
      s_j[n] = pj + emb_sj[node];
    }
  }
}

// ---- K3: edge softmax + aggregation + BN1 stats ----------------------------
__global__ __launch_bounds__(256) void k_edges(
    const float* __restrict__ xl, const float* __restrict__ s_i,
    const float* __restrict__ s_j, const int* __restrict__ topk,
    float* __restrict__ agg, float* __restrict__ gsum1, float* __restrict__ gss1) {
  int t = threadIdx.x, wv = t >> 6, ln = t & 63;
  __shared__ float red[2][4][64];
  float ps = 0.f, pss = 0.f;
  int base = blockIdx.x * 128;          // 128 nodes/block, grid 1024
  for (int it = 0; it < 32; it++) {
    int n = base + it * 4 + wv;         // wave-uniform dst node
    int node = n & (NNODE - 1);
    int boff = n - node;
    float sin = s_i[n];
    float al[KTOP]; int sr[KTOP];
    float m = -1e30f;
    #pragma unroll
    for (int k = 0; k < KTOP; k++) {
      int s = topk[node * KTOP + k] + boff;
      sr[k] = s;
      float a = sin + s_j[s];
      a = a > 0.f ? a : NEGS * a;       // leaky_relu
      al[k] = a;
      m = fmaxf(m, a);
    }
    float den = 0.f;
    #pragma unroll
    for (int k = 0; k < KTOP; k++) { al[k] = __expf(al[k] - m); den += al[k]; }
    float inv = 1.f / den;
    float a = 0.f;
    #pragma unroll
    for (int k = 0; k < KTOP; k++) a += al[k] * xl[sr[k] * EMBD + ln];
    a *= inv;
    agg[n * EMBD + ln] = a;
    ps += a; pss += a * a;
  }
  red[0][wv][ln] = ps; red[1][wv][ln] = pss;
  __syncthreads();
  if (t < 64) {
    atomicAdd(&gsum1[t], red[0][0][t] + red[0][1][t] + red[0][2][t] + red[0][3][t]);
  } else if (t < 128) {
    int e = t - 64;
    atomicAdd(&gss1[e], red[1][0][e] + red[1][1][e] + red[1][2][e] + red[1][3][e]);
  }
}

// ---- finalize BN coefficients: a = g*rsqrt(var+eps), c = b - mean*a --------
__global__ void k_fin(const float* __restrict__ gsum, const float* __restrict__ gss,
                      const float* __restrict__ g, const float* __restrict__ bb,
                      float* __restrict__ a, float* __restrict__ c, int C) {
  int e = blockIdx.x * blockDim.x + threadIdx.x;
  if (e >= C) return;
  const float invn = 1.f / (float)NTOT;
  float m = gsum[e] * invn;
  float v = gss[e] * invn - m * m;
  float aa = g[e] * rsqrtf(v + EPSBN);
  a[e] = aa;
  c[e] = bb[e] - m * aa;
}

// ---- K5: z = relu(bn1(agg)) * W_emb, BN2 stats -----------------------------
// (b_gnn cancels exactly inside training-mode BN: shift-invariant)
__global__ __launch_bounds__(256) void k_z(
    const float* __restrict__ agg, const float* __restrict__ W_emb,
    const float* __restrict__ a1, const float* __restrict__ c1,
    float* __restrict__ z, float* __restrict__ gsum2, float* __restrict__ gss2) {
  int t = threadIdx.x, wv = t >> 6, ln = t & 63;
  __shared__ float red[2][4][64];
  float aa = a1[ln], cc = c1[ln];
  float ps = 0.f, pss = 0.f;
  int stride = gridDim.x * 256;         // multiple of 64 -> channel fixed = ln
  for (int idx = blockIdx.x * 256 + t; idx < NTOT * EMBD; idx += stride) {
    int node = (idx >> 6) & (NNODE - 1);
    float h = agg[idx] * aa + cc;
    h = h > 0.f ? h : 0.f;
    float zz = h * W_emb[node * EMBD + ln];
    z[idx] = zz;
    ps += zz; pss += zz * zz;
  }
  red[0][wv][ln] = ps; red[1][wv][ln] = pss;
  __syncthreads();
  if (t < 64) {
    atomicAdd(&gsum2[t], red[0][0][t] + red[0][1][t] + red[0][2][t] + red[0][3][t]);
  } else if (t < 128) {
    int e = t - 64;
    atomicAdd(&gss2[e], red[1][0][e] + red[1][1][e] + red[1][2][e] + red[1][3][e]);
  }
}

// ============================================================================
// MFMA GEMM passes: z2[n,c] = relu(bn2(z[n,:])) @ W1[c,:]^T + b1[c], never
// materialized. 16x16x32 bf16 MFMA; A = h rows (bf16 on the fly), B = W1 cols
// (register-resident fragments). Block = 512 thr = 8 waves; wave wv owns cols
// [wv*64, wv*64+64) = 4 N-tiles. Each chunk = 16 rows.
//   A frag: lane holds h[m=lane&15][k=(lane>>4)*8 + j (+32*s)]
//   B frag: lane holds W1[n=col][k=(lane>>4)*8 + j (+32*s)]
//   D:      col = lane&15 (of tile), row = (lane>>4)*4 + reg
// ============================================================================

// ---- K7a: GEMM pass 1 — BN3 per-channel sum/sumsq only ---------------------
__global__ __launch_bounds__(512) void k_gstats(
    const float* __restrict__ z, const float* __restrict__ W1,
    const float* __restrict__ b1, const float* __restrict__ a2,
    const float* __restrict__ c2, float* __restrict__ gsum3,
    float* __restrict__ gss3) {
  int t = threadIdx.x, wv = t >> 6, ln = t & 63;
  int lm = ln & 15, lq = ln >> 4, kb = lq * 8;
  bf16x8 bfrag[4][2];
  float b1c[4];
  #pragma unroll
  for (int ti = 0; ti < 4; ti++) {
    int col = wv * 64 + ti * 16 + lm;
    b1c[ti] = b1[col];
    #pragma unroll
    for (int s = 0; s < 2; s++) {
      const float* wp = W1 + col * EMBD + s * 32 + kb;
      float4 w0 = *(const float4*)wp;
      float4 w1 = *(const float4*)(wp + 4);
      bf16x8 f;
      f[0] = (short)f2bf(w0.x); f[1] = (short)f2bf(w0.y);
      f[2] = (short)f2bf(w0.z); f[3] = (short)f2bf(w0.w);
      f[4] = (short)f2bf(w1.x); f[5] = (short)f2bf(w1.y);
      f[6] = (short)f2bf(w1.z); f[7] = (short)f2bf(w1.w);
      bfrag[ti][s] = f;
    }
  }
  float a2r[2][8], c2r[2][8];
  #pragma unroll
  for (int s = 0; s < 2; s++) {
    float4 x0 = *(const float4*)(a2 + s * 32 + kb);
    float4 x1 = *(const float4*)(a2 + s * 32 + kb + 4);
    a2r[s][0] = x0.x; a2r[s][1] = x0.y; a2r[s][2] = x0.z; a2r[s][3] = x0.w;
    a2r[s][4] = x1.x; a2r[s][5] = x1.y; a2r[s][6] = x1.z; a2r[s][7] = x1.w;
    float4 y0 = *(const float4*)(c2 + s * 32 + kb);
    float4 y1 = *(const float4*)(c2 + s * 32 + kb + 4);
    c2r[s][0] = y0.x; c2r[s][1] = y0.y; c2r[s][2] = y0.z; c2r[s][3] = y0.w;
    c2r[s][4] = y1.x; c2r[s][5] = y1.y; c2r[s][6] = y1.z; c2r[s][7] = y1.w;
  }
  float ssum[4] = {0.f, 0.f, 0.f, 0.f}, ssq[4] = {0.f, 0.f, 0.f, 0.f};
  for (int ch = blockIdx.x; ch < NTOT / 16; ch += gridDim.x) {
    const float* zr = z + (size_t)(ch * 16 + lm) * EMBD + kb;
    f32x4 acc[4];
    #pragma unroll
    for (int ti = 0; ti < 4; ti++) acc[ti] = (f32x4){0.f, 0.f, 0.f, 0.f};
    #pragma unroll
    for (int s = 0; s < 2; s++) {
      float4 z0 = *(const float4*)(zr + s * 32);
      float4 z1 = *(const float4*)(zr + s * 32 + 4);
      float hv[8] = {z0.x, z0.y, z0.z, z0.w, z1.x, z1.y, z1.z, z1.w};
      bf16x8 af;
      #pragma unroll
      for (int j = 0; j < 8; j++) {
        float h = hv[j] * a2r[s][j] + c2r[s][j];
        h = h > 0.f ? h : 0.f;
        af[j] = (short)f2bf(h);
      }
      #pragma unroll
      for (int ti = 0; ti < 4; ti++)
        acc[ti] = __builtin_amdgcn_mfma_f32_16x16x32_bf16(af, bfrag[ti][s], acc[ti], 0, 0, 0);
    }
    #pragma unroll
    for (int ti = 0; ti < 4; ti++) {
      #pragma unroll
      for (int r = 0; r < 4; r++) {
        float v = acc[ti][r] + b1c[ti];
        ssum[ti] += v; ssq[ti] += v * v;
      }
    }
  }
  #pragma unroll
  for (int ti = 0; ti < 4; ti++) {
    float s1 = ssum[ti], s2 = ssq[ti];
    s1 += __shfl_xor(s1, 16); s1 += __shfl_xor(s1, 32);
    s2 += __shfl_xor(s2, 16); s2 += __shfl_xor(s2, 32);
    if (lq == 0) {
      int col = wv * 64 + ti * 16 + lm;
      atomicAdd(&gsum3[col], s1);
      atomicAdd(&gss3[col], s2);
    }
  }
}

// ---- K7b: GEMM pass 2 — recompute z2, fuse BN3+relu+W2 dot -> out ----------
__global__ __launch_bounds__(512) void k_gout(
    const float* __restrict__ z, const float* __restrict__ W1,
    const float* __restrict__ b1, const float* __restrict__ a2,
    const float* __restrict__ c2, const float* __restrict__ a3,
    const float* __restrict__ c3, const float* __restrict__ W2,
    const float* __restrict__ b2, float* __restrict__ out) {
  __shared__ float part[8][16];
  int t = threadIdx.x, wv = t >> 6, ln = t & 63;
  int lm = ln & 15, lq = ln >> 4, kb = lq * 8;
  bf16x8 bfrag[4][2];
  float b1c[4], a3c[4], c3c[4], w2c[4];
  #pragma unroll
  for (int ti = 0; ti < 4; ti++) {
    int col = wv * 64 + ti * 16 + lm;
    b1c[ti] = b1[col]; a3c[ti] = a3[col]; c3c[ti] = c3[col]; w2c[ti] = W2[col];
    #pragma unroll
    for (int s = 0; s < 2; s++) {
      const float* wp = W1 + col * EMBD + s * 32 + kb;
      float4 w0 = *(const float4*)wp;
      float4 w1 = *(const float4*)(wp + 4);
      bf16x8 f;
      f[0] = (short)f2bf(w0.x); f[1] = (short)f2bf(w0.y);
      f[2] = (short)f2bf(w0.z); f[3] = (short)f2bf(w0.w);
      f[4] = (short)f2bf(w1.x); f[5] = (short)f2bf(w1.y);
      f[6] = (short)f2bf(w1.z); f[7] = (short)f2bf(w1.w);
      bfrag[ti][s] = f;
    }
  }
  float a2r[2][8], c2r[2][8];
  #pragma unroll
  for (int s = 0; s < 2; s++) {
    float4 x0 = *(const float4*)(a2 + s * 32 + kb);
    float4 x1 = *(const float4*)(a2 + s * 32 + kb + 4);
    a2r[s][0] = x0.x; a2r[s][1] = x0.y; a2r[s][2] = x0.z; a2r[s][3] = x0.w;
    a2r[s][4] = x1.x; a2r[s][5] = x1.y; a2r[s][6] = x1.z; a2r[s][7] = x1.w;
    float4 y0 = *(const float4*)(c2 + s * 32 + kb);
    float4 y1 = *(const float4*)(c2 + s * 32 + kb + 4);
    c2r[s][0] = y0.x; c2r[s][1] = y0.y; c2r[s][2] = y0.z; c2r[s][3] = y0.w;
    c2r[s][4] = y1.x; c2r[s][5] = y1.y; c2r[s][6] = y1.z; c2r[s][7] = y1.w;
  }
  float b2v = b2[0];
  for (int ch = blockIdx.x; ch < NTOT / 16; ch += gridDim.x) {
    const float* zr = z + (size_t)(ch * 16 + lm) * EMBD + kb;
    f32x4 acc[4];
    #pragma unroll
    for (int ti = 0; ti < 4; ti++) acc[ti] = (f32x4){0.f, 0.f, 0.f, 0.f};
    #pragma unroll
    for (int s = 0; s < 2; s++) {
      float4 z0 = *(const float4*)(zr + s * 32);
      float4 z1 = *(const float4*)(zr + s * 32 + 4);
      float hv[8] = {z0.x, z0.y, z0.z, z0.w, z1.x, z1.y, z1.z, z1.w};
      bf16x8 af;
      #pragma unroll
      for (int j = 0; j < 8; j++) {
        float h = hv[j] * a2r[s][j] + c2r[s][j];
        h = h > 0.f ? h : 0.f;
        af[j] = (short)f2bf(h);
      }
      #pragma unroll
      for (int ti = 0; ti < 4; ti++)
        acc[ti] = __builtin_amdgcn_mfma_f32_16x16x32_bf16(af, bfrag[ti][s], acc[ti], 0, 0, 0);
    }
    #pragma unroll
    for (int r = 0; r < 4; r++) {
      float p = 0.f;
      #pragma unroll
      for (int ti = 0; ti < 4; ti++) {
        float v = acc[ti][r] + b1c[ti];
        float y = v * a3c[ti] + c3c[ti];
        y = y > 0.f ? y : 0.f;
        p += y * w2c[ti];
      }
      p += __shfl_xor(p, 1); p += __shfl_xor(p, 2);
      p += __shfl_xor(p, 4); p += __shfl_xor(p, 8);
      if (lm == 0) part[wv][lq * 4 + r] = p;
    }
    __syncthreads();
    if (t < 16) {
      float s = 0.f;
      #pragma unroll
      for (int w = 0; w < 8; w++) s += part[w][t];
      out[ch * 16 + t] = s + b2v;
    }
    __syncthreads();
  }
}

extern "C" void kernel_launch(void* const* d_in, const int* in_sizes, int n_in,
                              void* d_out, int out_size, void* d_ws, size_t ws_size,
                              hipStream_t stream) {
  const float* data     = (const float*)d_in[0];
  // d_in[1] org_edge_index: unused by forward
  const float* W_emb    = (const float*)d_in[2];
  const float* W_lin    = (const float*)d_in[3];
  const float* att_i    = (const float*)d_in[4];
  const float* att_j    = (const float*)d_in[5];
  const float* att_em_i = (const float*)d_in[6];
  const float* att_em_j = (const float*)d_in[7];
  // d_in[8] b_gnn: cancels exactly inside training-mode BN1
  const float* g_bn1    = (const float*)d_in[9];
  const float* b_bn1    = (const float*)d_in[10];
  const float* g_bn2    = (const float*)d_in[11];
  const float* b_bn2    = (const float*)d_in[12];
  const float* W1       = (const float*)d_in[13];
  const float* b1       = (const float*)d_in[14];
  const float* g_bn3    = (const float*)d_in[15];
  const float* b_bn3    = (const float*)d_in[16];
  const float* W2       = (const float*)d_in[17];
  const float* b2       = (const float*)d_in[18];
  float* out = (float*)d_out;

  char* p = (char*)d_ws;
  auto alloc = [&](size_t bytes) {
    void* r = (void*)p;
    p += (bytes + 255) & ~(size_t)255;
    return r;
  };
  float* xl   = (float*)alloc((size_t)NTOT * EMBD * 4);  // reused as z after k_edges
  float* agg  = (float*)alloc((size_t)NTOT * EMBD * 4);
  float* s_i  = (float*)alloc((size_t)NTOT * 4);
  float* s_j  = (float*)alloc((size_t)NTOT * 4);
  float* nw   = (float*)alloc((size_t)NNODE * EMBD * 4);
  float* emb_si = (float*)alloc(NNODE * 4);
  float* emb_sj = (float*)alloc(NNODE * 4);
  int*   topk   = (int*)alloc(NNODE * KTOP * 4);
  float* stats  = (float*)alloc((64 * 4 + 512 * 2) * 4);  // sums/sumsqs
  float* coefs  = (float*)alloc((64 * 4 + 512 * 2) * 4);  // a/c per BN

  float* gsum1 = stats;       float* gss1 = stats + 64;
  float* gsum2 = stats + 128; float* gss2 = stats + 192;
  float* gsum3 = stats + 256; float* gss3 = stats + 768;
  float* a1 = coefs;       float* c1 = coefs + 64;
  float* a2 = coefs + 128; float* c2 = coefs + 192;
  float* a3 = coefs + 256; float* c3 = coefs + 768;
  float* zbuf = xl;   // xl is dead after k_edges

  hipMemsetAsync(stats, 0, (64 * 4 + 512 * 2) * 4, stream);

  k_prep<<<NNODE, 64, 0, stream>>>(W_emb, att_em_i, att_em_j, nw, emb_si, emb_sj);
  k_topk<<<NNODE, 256, 0, stream>>>(nw, topk);
  k_lin<<<NTOT / 64, 256, 0, stream>>>(data, W_lin, att_i, att_j, emb_si, emb_sj,
                                       xl, s_i, s_j);
  k_edges<<<NTOT / 128, 256, 0, stream>>>(xl, s_i, s_j, topk, agg, gsum1, gss1);
  k_fin<<<1, 64, 0, stream>>>(gsum1, gss1, g_bn1, b_bn1, a1, c1, EMBD);
  k_z<<<1024, 256, 0, stream>>>(agg, W_emb, a1, c1, zbuf, gsum2, gss2);
  k_fin<<<1, 64, 0, stream>>>(gsum2, gss2, g_bn2, b_bn2, a2, c2, EMBD);
  k_gstats<<<1024, 512, 0, stream>>>(zbuf, W1, b1, a2, c2, gsum3, gss3);
  k_fin<<<1, 512, 0, stream>>>(gsum3, gss3, g_bn3, b_bn3, a3, c3, CIN);
  k_gout<<<1024, 512, 0, stream>>>(zbuf, W1, b1, a2, c2, a3, c3, W2, b2, out);
}

// Round 3
// 408.185 us; speedup vs baseline: 2.1066x; 1.0541x over previous
//
#include <hip/hip_runtime.h>
#include <hip/hip_bf16.h>

constexpr int BATCH = 256, NNODE = 512, WINW = 64, EMBD = 64, KTOP = 16, CIN = 512;
constexpr int NTOT = BATCH * NNODE;          // 131072
constexpr float NEGS = 0.2f;
constexpr float EPSBN = 1e-5f;

typedef __attribute__((ext_vector_type(8))) short bf16x8;
typedef __attribute__((ext_vector_type(4))) float f32x4;

__device__ inline unsigned short f2bf(float x) {
  union { float f; unsigned u; } v; v.f = x;
  unsigned r = v.u + 0x7fff + ((v.u >> 16) & 1);   // RNE
  return (unsigned short)(r >> 16);
}

// ---- K0: normalize embeddings + per-node attention-embedding dots ----------
__global__ void k_prep(const float* __restrict__ W_emb,
                       const float* __restrict__ att_em_i,
                       const float* __restrict__ att_em_j,
                       float* __restrict__ nw, float* __restrict__ emb_si,
                       float* __restrict__ emb_sj) {
  int i = blockIdx.x, e = threadIdx.x;   // block = 64 threads
  float w  = W_emb[i * EMBD + e];
  float sq = w * w;
  float si = w * att_em_i[e];
  float sj = w * att_em_j[e];
  for (int o = 32; o > 0; o >>= 1) {
    sq += __shfl_xor(sq, o);
    si += __shfl_xor(si, o);
    sj += __shfl_xor(sj, o);
  }
  nw[i * EMBD + e] = w * rsqrtf(sq);
  if (e == 0) { emb_si[i] = si; emb_sj[i] = sj; }
}

// ---- K1: cosine top-16 per node — shuffle argmax, 2 barriers per select ----
__global__ __launch_bounds__(256) void k_topk(const float* __restrict__ nw,
                                              int* __restrict__ topk) {
  __shared__ float nwi[EMBD];
  __shared__ float wbv[4];
  __shared__ int   wbi[4];
  __shared__ int   winner;
  int i = blockIdx.x, t = threadIdx.x, wv = t >> 6, ln = t & 63;
  if (t < EMBD) nwi[t] = nw[i * EMBD + t];
  __syncthreads();
  float v0 = 0.f, v1 = 0.f;
  #pragma unroll
  for (int k = 0; k < EMBD; k++) {
    v0 += nw[t * EMBD + k] * nwi[k];
    v1 += nw[(t + 256) * EMBD + k] * nwi[k];
  }
  for (int sel = 0; sel < KTOP; sel++) {
    float bv; int bi;
    if (v1 > v0) { bv = v1; bi = t + 256; } else { bv = v0; bi = t; }  // tie -> lower idx
    #pragma unroll
    for (int o = 1; o < 64; o <<= 1) {
      float ov = __shfl_xor(bv, o);
      int   oi = __shfl_xor(bi, o);
      if (ov > bv || (ov == bv && oi < bi)) { bv = ov; bi = oi; }
    }
    if (ln == 0) { wbv[wv] = bv; wbi[wv] = bi; }
    __syncthreads();
    if (t == 0) {
      float B = wbv[0]; int I = wbi[0];
      #pragma unroll
      for (int w = 1; w < 4; w++)
        if (wbv[w] > B || (wbv[w] == B && wbi[w] < I)) { B = wbv[w]; I = wbi[w]; }
      topk[i * KTOP + sel] = I;
      winner = I;
    }
    __syncthreads();
    int wi = winner;
    if (wi == t) v0 = -3.f;
    else if (wi == t + 256) v1 = -3.f;
  }
}

// ============================================================================
// K_FUSE: one block per batch (grid=256, 1024 thr = 16 waves).
// Phase A: xl = x @ W_lin^T via bf16 MFMA -> LDS (fp32, 128 KB), s_i/s_j -> LDS.
// Phase B: per-dst softmax over 16 LDS-resident neighbors, weighted agg,
//          write agg to global + BN1 per-channel stats.
// ============================================================================
__global__ __launch_bounds__(1024) void k_fuse(
    const float* __restrict__ data, const float* __restrict__ W_lin,
    const float* __restrict__ att_i, const float* __restrict__ att_j,
    const float* __restrict__ emb_si, const float* __restrict__ emb_sj,
    const int* __restrict__ topk,
    float* __restrict__ agg, float* __restrict__ gsum1, float* __restrict__ gss1) {
  __shared__ float xl[NNODE * EMBD];      // 128 KB
  __shared__ float ssi[NNODE];            // 2 KB
  __shared__ float ssj[NNODE];            // 2 KB
  __shared__ float redb[16 * 128];        // 8 KB
  const int b = blockIdx.x;
  const int t = threadIdx.x, w = t >> 6, ln = t & 63;
  const int lm = ln & 15, lq = ln >> 4, kb = lq * 8;

  // B-fragments (W_lin rows = output channels) + att coefs
  bf16x8 bfrag[4][2];
  float ai4[4], aj4[4];
  #pragma unroll
  for (int ti = 0; ti < 4; ti++) {
    int ch = ti * 16 + lm;
    ai4[ti] = att_i[ch]; aj4[ti] = att_j[ch];
    #pragma unroll
    for (int s = 0; s < 2; s++) {
      const float* wp = W_lin + ch * WINW + s * 32 + kb;
      float4 w0 = *(const float4*)wp;
      float4 w1 = *(const float4*)(wp + 4);
      bf16x8 f;
      f[0] = (short)f2bf(w0.x); f[1] = (short)f2bf(w0.y);
      f[2] = (short)f2bf(w0.z); f[3] = (short)f2bf(w0.w);
      f[4] = (short)f2bf(w1.x); f[5] = (short)f2bf(w1.y);
      f[6] = (short)f2bf(w1.z); f[7] = (short)f2bf(w1.w);
      bfrag[ti][s] = f;
    }
  }
  // ---- phase A: 2 M-tiles (16 rows each) per wave
  #pragma unroll
  for (int tt = 0; tt < 2; tt++) {
    int tile = w * 2 + tt;
    const float* dr = data + ((size_t)b * NNODE + tile * 16 + lm) * WINW + kb;
    f32x4 acc[4];
    #pragma unroll
    for (int ti = 0; ti < 4; ti++) acc[ti] = (f32x4){0.f, 0.f, 0.f, 0.f};
    #pragma unroll
    for (int s = 0; s < 2; s++) {
      float4 d0 = *(const float4*)(dr + s * 32);
      float4 d1 = *(const float4*)(dr + s * 32 + 4);
      bf16x8 af;
      af[0] = (short)f2bf(d0.x); af[1] = (short)f2bf(d0.y);
      af[2] = (short)f2bf(d0.z); af[3] = (short)f2bf(d0.w);
      af[4] = (short)f2bf(d1.x); af[5] = (short)f2bf(d1.y);
      af[6] = (short)f2bf(d1.z); af[7] = (short)f2bf(d1.w);
      #pragma unroll
      for (int ti = 0; ti < 4; ti++)
        acc[ti] = __builtin_amdgcn_mfma_f32_16x16x32_bf16(af, bfrag[ti][s], acc[ti], 0, 0, 0);
    }
    #pragma unroll
    for (int r = 0; r < 4; r++) {
      int nd = tile * 16 + lq * 4 + r;
      float si = 0.f, sj = 0.f;
      #pragma unroll
      for (int ti = 0; ti < 4; ti++) {
        float v = acc[ti][r];
        xl[nd * EMBD + ti * 16 + lm] = v;
        si += v * ai4[ti];
        sj += v * aj4[ti];
      }
      si += __shfl_xor(si, 1); si += __shfl_xor(si, 2);
      si += __shfl_xor(si, 4); si += __shfl_xor(si, 8);
      sj += __shfl_xor(sj, 1); sj += __shfl_xor(sj, 2);
      sj += __shfl_xor(sj, 4); sj += __shfl_xor(sj, 8);
      if (lm == 0) { ssi[nd] = si + emb_si[nd]; ssj[nd] = sj + emb_sj[nd]; }
    }
  }
  __syncthreads();
  // ---- phase B: 4 dst nodes per wave-pass; lane = (nd4, l4)
  const int nd4 = ln >> 4, l4 = ln & 15;
  float psx = 0.f, psy = 0.f, psz = 0.f, psw = 0.f;
  float qsx = 0.f, qsy = 0.f, qsz = 0.f, qsw = 0.f;
  for (int it = 0; it < 8; it++) {
    int node = w * 32 + it * 4 + nd4;
    const int4* tp = (const int4*)(topk + node * KTOP);
    int4 i0 = tp[0], i1 = tp[1], i2 = tp[2], i3 = tp[3];
    int idx[16] = {i0.x, i0.y, i0.z, i0.w, i1.x, i1.y, i1.z, i1.w,
                   i2.x, i2.y, i2.z, i2.w, i3.x, i3.y, i3.z, i3.w};
    float sid = ssi[node];
    float al[16], mx = -1e30f;
    #pragma unroll
    for (int k = 0; k < KTOP; k++) {
      float a = sid + ssj[idx[k]];
      a = a > 0.f ? a : NEGS * a;        // leaky_relu
      al[k] = a;
      mx = fmaxf(mx, a);
    }
    float den = 0.f;
    #pragma unroll
    for (int k = 0; k < KTOP; k++) { al[k] = __expf(al[k] - mx); den += al[k]; }
    float inv = 1.f / den;
    float ax = 0.f, ay = 0.f, az = 0.f, aw = 0.f;
    #pragma unroll
    for (int k = 0; k < KTOP; k++) {
      float4 v = *(const float4*)&xl[idx[k] * EMBD + l4 * 4];
      ax += al[k] * v.x; ay += al[k] * v.y; az += al[k] * v.z; aw += al[k] * v.w;
    }
    ax *= inv; ay *= inv; az *= inv; aw *= inv;
    float4 st = {ax, ay, az, aw};
    *(float4*)(agg + ((size_t)b * NNODE + node) * EMBD + l4 * 4) = st;
    psx += ax; psy += ay; psz += az; psw += aw;
    qsx += ax * ax; qsy += ay * ay; qsz += az * az; qsw += aw * aw;
  }
  // reduce across the 4 nd4 groups (lanes differ in bits 4,5)
  #pragma unroll
  for (int o = 16; o <= 32; o <<= 1) {
    psx += __shfl_xor(psx, o); psy += __shfl_xor(psy, o);
    psz += __shfl_xor(psz, o); psw += __shfl_xor(psw, o);
    qsx += __shfl_xor(qsx, o); qsy += __shfl_xor(qsy, o);
    qsz += __shfl_xor(qsz, o); qsw += __shfl_xor(qsw, o);
  }
  if (ln < 16) {
    float4 a = {psx, psy, psz, psw};
    float4 q = {qsx, qsy, qsz, qsw};
    *(float4*)&redb[w * 128 + ln * 4] = a;
    *(float4*)&redb[w * 128 + 64 + ln * 4] = q;
  }
  __syncthreads();
  if (t < 64) {
    float s = 0.f;
    #pragma unroll
    for (int w16 = 0; w16 < 16; w16++) s += redb[w16 * 128 + t];
    atomicAdd(&gsum1[t], s);
  } else if (t < 128) {
    int e = t - 64;
    float s = 0.f;
    #pragma unroll
    for (int w16 = 0; w16 < 16; w16++) s += redb[w16 * 128 + 64 + e];
    atomicAdd(&gss1[e], s);
  }
}

// ---- finalize BN coefficients: a = g*rsqrt(var+eps), c = b - mean*a --------
__global__ void k_fin(const float* __restrict__ gsum, const float* __restrict__ gss,
                      const float* __restrict__ g, const float* __restrict__ bb,
                      float* __restrict__ a, float* __restrict__ c, int C) {
  int e = blockIdx.x * blockDim.x + threadIdx.x;
  if (e >= C) return;
  const float invn = 1.f / (float)NTOT;
  float m = gsum[e] * invn;
  float v = gss[e] * invn - m * m;
  float aa = g[e] * rsqrtf(v + EPSBN);
  a[e] = aa;
  c[e] = bb[e] - m * aa;
}

// ---- K5: BN2 stats over z = relu(bn1(agg))*W_emb (z never materialized) ----
__global__ __launch_bounds__(256) void k_zstats(
    const float* __restrict__ agg, const float* __restrict__ W_emb,
    const float* __restrict__ a1, const float* __restrict__ c1,
    float* __restrict__ gsum2, float* __restrict__ gss2) {
  int t = threadIdx.x, wv = t >> 6, ln = t & 63;
  __shared__ float red[2][4][64];
  float aa = a1[ln], cc = c1[ln];
  float ps = 0.f, pss = 0.f;
  int stride = gridDim.x * 256;         // multiple of 64 -> channel fixed = ln
  for (int idx = blockIdx.x * 256 + t; idx < NTOT * EMBD; idx += stride) {
    int node = (idx >> 6) & (NNODE - 1);
    float h = agg[idx] * aa + cc;
    h = h > 0.f ? h : 0.f;
    float zz = h * W_emb[node * EMBD + ln];
    ps += zz; pss += zz * zz;
  }
  red[0][wv][ln] = ps; red[1][wv][ln] = pss;
  __syncthreads();
  if (t < 64) {
    atomicAdd(&gsum2[t], red[0][0][t] + red[0][1][t] + red[0][2][t] + red[0][3][t]);
  } else if (t < 128) {
    int e = t - 64;
    atomicAdd(&gss2[e], red[1][0][e] + red[1][1][e] + red[1][2][e] + red[1][3][e]);
  }
}

// ============================================================================
// MFMA GEMM passes over z2 = relu(bn2(z)) @ W1^T + b1 (z recomputed inline
// from agg; z2 never materialized). Block = 512 thr = 8 waves.
// ============================================================================

// ---- K7a: GEMM pass 1 — BN3 per-channel sum/sumsq --------------------------
__global__ __launch_bounds__(512) void k_gstats(
    const float* __restrict__ agg, const float* __restrict__ W_emb,
    const float* __restrict__ W1, const float* __restrict__ b1,
    const float* __restrict__ a1, const float* __restrict__ c1,
    const float* __restrict__ a2, const float* __restrict__ c2,
    float* __restrict__ gsum3, float* __restrict__ gss3) {
  int t = threadIdx.x, wv = t >> 6, ln = t & 63;
  int lm = ln & 15, lq = ln >> 4, kb = lq * 8;
  bf16x8 bfrag[4][2];
  float b1c[4];
  #pragma unroll
  for (int ti = 0; ti < 4; ti++) {
    int col = wv * 64 + ti * 16 + lm;
    b1c[ti] = b1[col];
    #pragma unroll
    for (int s = 0; s < 2; s++) {
      const float* wp = W1 + col * EMBD + s * 32 + kb;
      float4 w0 = *(const float4*)wp;
      float4 w1 = *(const float4*)(wp + 4);
      bf16x8 f;
      f[0] = (short)f2bf(w0.x); f[1] = (short)f2bf(w0.y);
      f[2] = (short)f2bf(w0.z); f[3] = (short)f2bf(w0.w);
      f[4] = (short)f2bf(w1.x); f[5] = (short)f2bf(w1.y);
      f[6] = (short)f2bf(w1.z); f[7] = (short)f2bf(w1.w);
      bfrag[ti][s] = f;
    }
  }
  float a1r[2][8], c1r[2][8], a2r[2][8], c2r[2][8];
  #pragma unroll
  for (int s = 0; s < 2; s++) {
    #pragma unroll
    for (int j = 0; j < 8; j++) {
      a1r[s][j] = a1[s * 32 + kb + j]; c1r[s][j] = c1[s * 32 + kb + j];
      a2r[s][j] = a2[s * 32 + kb + j]; c2r[s][j] = c2[s * 32 + kb + j];
    }
  }
  float ssum[4] = {0.f, 0.f, 0.f, 0.f}, ssq[4] = {0.f, 0.f, 0.f, 0.f};
  for (int ch = blockIdx.x; ch < NTOT / 16; ch += gridDim.x) {
    int row = ch * 16 + lm;
    const float* ar = agg + (size_t)row * EMBD + kb;
    const float* er = W_emb + (size_t)(row & (NNODE - 1)) * EMBD + kb;
    f32x4 acc[4];
    #pragma unroll
    for (int ti = 0; ti < 4; ti++) acc[ti] = (f32x4){0.f, 0.f, 0.f, 0.f};
    #pragma unroll
    for (int s = 0; s < 2; s++) {
      float4 g0 = *(const float4*)(ar + s * 32);
      float4 g1 = *(const float4*)(ar + s * 32 + 4);
      float4 e0 = *(const float4*)(er + s * 32);
      float4 e1 = *(const float4*)(er + s * 32 + 4);
      float gv[8] = {g0.x, g0.y, g0.z, g0.w, g1.x, g1.y, g1.z, g1.w};
      float ev[8] = {e0.x, e0.y, e0.z, e0.w, e1.x, e1.y, e1.z, e1.w};
      bf16x8 af;
      #pragma unroll
      for (int j = 0; j < 8; j++) {
        float zz = gv[j] * a1r[s][j] + c1r[s][j];
        zz = zz > 0.f ? zz : 0.f;
        zz *= ev[j];
        float h = zz * a2r[s][j] + c2r[s][j];
        h = h > 0.f ? h : 0.f;
        af[j] = (short)f2bf(h);
      }
      #pragma unroll
      for (int ti = 0; ti < 4; ti++)
        acc[ti] = __builtin_amdgcn_mfma_f32_16x16x32_bf16(af, bfrag[ti][s], acc[ti], 0, 0, 0);
    }
    #pragma unroll
    for (int ti = 0; ti < 4; ti++) {
      #pragma unroll
      for (int r = 0; r < 4; r++) {
        float v = acc[ti][r] + b1c[ti];
        ssum[ti] += v; ssq[ti] += v * v;
      }
    }
  }
  #pragma unroll
  for (int ti = 0; ti < 4; ti++) {
    float s1 = ssum[ti], s2 = ssq[ti];
    s1 += __shfl_xor(s1, 16); s1 += __shfl_xor(s1, 32);
    s2 += __shfl_xor(s2, 16); s2 += __shfl_xor(s2, 32);
    if (lq == 0) {
      int col = wv * 64 + ti * 16 + lm;
      atomicAdd(&gsum3[col], s1);
      atomicAdd(&gss3[col], s2);
    }
  }
}

// ---- K7b: GEMM pass 2 — recompute z2, fuse BN3+relu+W2 dot -> out ----------
__global__ __launch_bounds__(512) void k_gout(
    const float* __restrict__ agg, const float* __restrict__ W_emb,
    const float* __restrict__ W1, const float* __restrict__ b1,
    const float* __restrict__ a1, const float* __restrict__ c1,
    const float* __restrict__ a2, const float* __restrict__ c2,
    const float* __restrict__ a3, const float* __restrict__ c3,
    const float* __restrict__ W2, const float* __restrict__ b2,
    float* __restrict__ out) {
  __shared__ float part[8][16];
  int t = threadIdx.x, wv = t >> 6, ln = t & 63;
  int lm = ln & 15, lq = ln >> 4, kb = lq * 8;
  bf16x8 bfrag[4][2];
  float b1c[4], a3c[4], c3c[4], w2c[4];
  #pragma unroll
  for (int ti = 0; ti < 4; ti++) {
    int col = wv * 64 + ti * 16 + lm;
    b1c[ti] = b1[col]; a3c[ti] = a3[col]; c3c[ti] = c3[col]; w2c[ti] = W2[col];
    #pragma unroll
    for (int s = 0; s < 2; s++) {
      const float* wp = W1 + col * EMBD + s * 32 + kb;
      float4 w0 = *(const float4*)wp;
      float4 w1 = *(const float4*)(wp + 4);
      bf16x8 f;
      f[0] = (short)f2bf(w0.x); f[1] = (short)f2bf(w0.y);
      f[2] = (short)f2bf(w0.z); f[3] = (short)f2bf(w0.w);
      f[4] = (short)f2bf(w1.x); f[5] = (short)f2bf(w1.y);
      f[6] = (short)f2bf(w1.z); f[7] = (short)f2bf(w1.w);
      bfrag[ti][s] = f;
    }
  }
  float a1r[2][8], c1r[2][8], a2r[2][8], c2r[2][8];
  #pragma unroll
  for (int s = 0; s < 2; s++) {
    #pragma unroll
    for (int j = 0; j < 8; j++) {
      a1r[s][j] = a1[s * 32 + kb + j]; c1r[s][j] = c1[s * 32 + kb + j];
      a2r[s][j] = a2[s * 32 + kb + j]; c2r[s][j] = c2[s * 32 + kb + j];
    }
  }
  float b2v = b2[0];
  for (int ch = blockIdx.x; ch < NTOT / 16; ch += gridDim.x) {
    int row = ch * 16 + lm;
    const float* ar = agg + (size_t)row * EMBD + kb;
    const float* er = W_emb + (size_t)(row & (NNODE - 1)) * EMBD + kb;
    f32x4 acc[4];
    #pragma unroll
    for (int ti = 0; ti < 4; ti++) acc[ti] = (f32x4){0.f, 0.f, 0.f, 0.f};
    #pragma unroll
    for (int s = 0; s < 2; s++) {
      float4 g0 = *(const float4*)(ar + s * 32);
      float4 g1 = *(const float4*)(ar + s * 32 + 4);
      float4 e0 = *(const float4*)(er + s * 32);
      float4 e1 = *(const float4*)(er + s * 32 + 4);
      float gv[8] = {g0.x, g0.y, g0.z, g0.w, g1.x, g1.y, g1.z, g1.w};
      float ev[8] = {e0.x, e0.y, e0.z, e0.w, e1.x, e1.y, e1.z, e1.w};
      bf16x8 af;
      #pragma unroll
      for (int j = 0; j < 8; j++) {
        float zz = gv[j] * a1r[s][j] + c1r[s][j];
        zz = zz > 0.f ? zz : 0.f;
        zz *= ev[j];
        float h = zz * a2r[s][j] + c2r[s][j];
        h = h > 0.f ? h : 0.f;
        af[j] = (short)f2bf(h);
      }
      #pragma unroll
      for (int ti = 0; ti < 4; ti++)
        acc[ti] = __builtin_amdgcn_mfma_f32_16x16x32_bf16(af, bfrag[ti][s], acc[ti], 0, 0, 0);
    }
    #pragma unroll
    for (int r = 0; r < 4; r++) {
      float p = 0.f;
      #pragma unroll
      for (int ti = 0; ti < 4; ti++) {
        float v = acc[ti][r] + b1c[ti];
        float y = v * a3c[ti] + c3c[ti];
        y = y > 0.f ? y : 0.f;
        p += y * w2c[ti];
      }
      p += __shfl_xor(p, 1); p += __shfl_xor(p, 2);
      p += __shfl_xor(p, 4); p += __shfl_xor(p, 8);
      if (lm == 0) part[wv][lq * 4 + r] = p;
    }
    __syncthreads();
    if (t < 16) {
      float s = 0.f;
      #pragma unroll
      for (int w = 0; w < 8; w++) s += part[w][t];
      out[ch * 16 + t] = s + b2v;
    }
    __syncthreads();
  }
}

extern "C" void kernel_launch(void* const* d_in, const int* in_sizes, int n_in,
                              void* d_out, int out_size, void* d_ws, size_t ws_size,
                              hipStream_t stream) {
  const float* data     = (const float*)d_in[0];
  // d_in[1] org_edge_index: unused by forward
  const float* W_emb    = (const float*)d_in[2];
  const float* W_lin    = (const float*)d_in[3];
  const float* att_i    = (const float*)d_in[4];
  const float* att_j    = (const float*)d_in[5];
  const float* att_em_i = (const float*)d_in[6];
  const float* att_em_j = (const float*)d_in[7];
  // d_in[8] b_gnn: cancels exactly inside training-mode BN1
  const float* g_bn1    = (const float*)d_in[9];
  const float* b_bn1    = (const float*)d_in[10];
  const float* g_bn2    = (const float*)d_in[11];
  const float* b_bn2    = (const float*)d_in[12];
  const float* W1       = (const float*)d_in[13];
  const float* b1       = (const float*)d_in[14];
  const float* g_bn3    = (const float*)d_in[15];
  const float* b_bn3    = (const float*)d_in[16];
  const float* W2       = (const float*)d_in[17];
  const float* b2       = (const float*)d_in[18];
  float* out = (float*)d_out;

  char* p = (char*)d_ws;
  auto alloc = [&](size_t bytes) {
    void* r = (void*)p;
    p += (bytes + 255) & ~(size_t)255;
    return r;
  };
  float* agg    = (float*)alloc((size_t)NTOT * EMBD * 4);   // 33.5 MB
  float* nw     = (float*)alloc((size_t)NNODE * EMBD * 4);
  float* emb_si = (float*)alloc(NNODE * 4);
  float* emb_sj = (float*)alloc(NNODE * 4);
  int*   topk   = (int*)alloc(NNODE * KTOP * 4);
  float* stats  = (float*)alloc((64 * 4 + 512 * 2) * 4);    // sums/sumsqs
  float* coefs  = (float*)alloc((64 * 4 + 512 * 2) * 4);    // a/c per BN

  float* gsum1 = stats;       float* gss1 = stats + 64;
  float* gsum2 = stats + 128; float* gss2 = stats + 192;
  float* gsum3 = stats + 256; float* gss3 = stats + 768;
  float* a1 = coefs;       float* c1 = coefs + 64;
  float* a2 = coefs + 128; float* c2 = coefs + 192;
  float* a3 = coefs + 256; float* c3 = coefs + 768;

  hipMemsetAsync(stats, 0, (64 * 4 + 512 * 2) * 4, stream);

  k_prep<<<NNODE, 64, 0, stream>>>(W_emb, att_em_i, att_em_j, nw, emb_si, emb_sj);
  k_topk<<<NNODE, 256, 0, stream>>>(nw, topk);
  k_fuse<<<BATCH, 1024, 0, stream>>>(data, W_lin, att_i, att_j, emb_si, emb_sj,
                                     topk, agg, gsum1, gss1);
  k_fin<<<1, 64, 0, stream>>>(gsum1, gss1, g_bn1, b_bn1, a1, c1, EMBD);
  k_zstats<<<1024, 256, 0, stream>>>(agg, W_emb, a1, c1, gsum2, gss2);
  k_fin<<<1, 64, 0, stream>>>(gsum2, gss2, g_bn2, b_bn2, a2, c2, EMBD);
  k_gstats<<<1024, 512, 0, stream>>>(agg, W_emb, W1, b1, a1, c1, a2, c2, gsum3, gss3);
  k_fin<<<1, 512, 0, stream>>>(gsum3, gss3, g_bn3, b_bn3, a3, c3, CIN);
  k_gout<<<1024, 512, 0, stream>>>(agg, W_emb, W1, b1, a1, c1, a2, c2, a3, c3, W2, b2, out);
}

// Round 4
// 285.394 us; speedup vs baseline: 3.0130x; 1.4303x over previous
//
#include <hip/hip_runtime.h>
#include <hip/hip_bf16.h>

constexpr int BATCH = 256, NNODE = 512, WINW = 64, EMBD = 64, KTOP = 16, CIN = 512;
constexpr int NTOT = BATCH * NNODE;          // 131072
constexpr float NEGS = 0.2f;
constexpr float EPSBN = 1e-5f;

typedef __attribute__((ext_vector_type(8))) short bf16x8;
typedef __attribute__((ext_vector_type(4))) float f32x4;

__device__ inline float bf2f(unsigned u16) {
  union { unsigned u; float f; } v; v.u = u16 << 16; return v.f;
}
__device__ inline unsigned short f2bf(float x) {
  union { float f; unsigned u; } v; v.f = x;
  unsigned r = v.u + 0x7fff + ((v.u >> 16) & 1);   // RNE
  return (unsigned short)(r >> 16);
}

// ---- K0: normalize embeddings + per-node attention-embedding dots ----------
__global__ void k_prep(const float* __restrict__ W_emb,
                       const float* __restrict__ att_em_i,
                       const float* __restrict__ att_em_j,
                       float* __restrict__ nw, float* __restrict__ emb_si,
                       float* __restrict__ emb_sj) {
  int i = blockIdx.x, e = threadIdx.x;   // block = 64 threads
  float w  = W_emb[i * EMBD + e];
  float sq = w * w;
  float si = w * att_em_i[e];
  float sj = w * att_em_j[e];
  for (int o = 32; o > 0; o >>= 1) {
    sq += __shfl_xor(sq, o);
    si += __shfl_xor(si, o);
    sj += __shfl_xor(sj, o);
  }
  nw[i * EMBD + e] = w * rsqrtf(sq);
  if (e == 0) { emb_si[i] = si; emb_sj[i] = sj; }
}

// ---- K1: cosine top-16 per node — shuffle argmax ---------------------------
__global__ __launch_bounds__(256) void k_topk(const float* __restrict__ nw,
                                              int* __restrict__ topk) {
  __shared__ float nwi[EMBD];
  __shared__ float wbv[4];
  __shared__ int   wbi[4];
  __shared__ int   winner;
  int i = blockIdx.x, t = threadIdx.x, wv = t >> 6, ln = t & 63;
  if (t < EMBD) nwi[t] = nw[i * EMBD + t];
  __syncthreads();
  float v0 = 0.f, v1 = 0.f;
  #pragma unroll
  for (int k = 0; k < EMBD; k++) {
    v0 += nw[t * EMBD + k] * nwi[k];
    v1 += nw[(t + 256) * EMBD + k] * nwi[k];
  }
  for (int sel = 0; sel < KTOP; sel++) {
    float bv; int bi;
    if (v1 > v0) { bv = v1; bi = t + 256; } else { bv = v0; bi = t; }  // tie -> lower idx
    #pragma unroll
    for (int o = 1; o < 64; o <<= 1) {
      float ov = __shfl_xor(bv, o);
      int   oi = __shfl_xor(bi, o);
      if (ov > bv || (ov == bv && oi < bi)) { bv = ov; bi = oi; }
    }
    if (ln == 0) { wbv[wv] = bv; wbi[wv] = bi; }
    __syncthreads();
    if (t == 0) {
      float B = wbv[0]; int I = wbi[0];
      #pragma unroll
      for (int w = 1; w < 4; w++)
        if (wbv[w] > B || (wbv[w] == B && wbi[w] < I)) { B = wbv[w]; I = wbi[w]; }
      topk[i * KTOP + sel] = I;
      winner = I;
    }
    __syncthreads();
    int wi = winner;
    if (wi == t) v0 = -3.f;
    else if (wi == t + 256) v1 = -3.f;
  }
}

// ============================================================================
// K_FUSE: one block per batch (grid=256, 1024 thr = 16 waves).
// Phase A: xl = x @ W_lin^T via bf16 MFMA -> LDS; Phase B: softmax+agg.
// ============================================================================
__global__ __launch_bounds__(1024) void k_fuse(
    const float* __restrict__ data, const float* __restrict__ W_lin,
    const float* __restrict__ att_i, const float* __restrict__ att_j,
    const float* __restrict__ emb_si, const float* __restrict__ emb_sj,
    const int* __restrict__ topk,
    float* __restrict__ agg, float* __restrict__ gsum1, float* __restrict__ gss1) {
  __shared__ float xl[NNODE * EMBD];      // 128 KB
  __shared__ float ssi[NNODE];
  __shared__ float ssj[NNODE];
  __shared__ float redb[16 * 128];
  const int b = blockIdx.x;
  const int t = threadIdx.x, w = t >> 6, ln = t & 63;
  const int lm = ln & 15, lq = ln >> 4, kb = lq * 8;

  bf16x8 bfrag[4][2];
  float ai4[4], aj4[4];
  #pragma unroll
  for (int ti = 0; ti < 4; ti++) {
    int ch = ti * 16 + lm;
    ai4[ti] = att_i[ch]; aj4[ti] = att_j[ch];
    #pragma unroll
    for (int s = 0; s < 2; s++) {
      const float* wp = W_lin + ch * WINW + s * 32 + kb;
      float4 w0 = *(const float4*)wp;
      float4 w1 = *(const float4*)(wp + 4);
      bf16x8 f;
      f[0] = (short)f2bf(w0.x); f[1] = (short)f2bf(w0.y);
      f[2] = (short)f2bf(w0.z); f[3] = (short)f2bf(w0.w);
      f[4] = (short)f2bf(w1.x); f[5] = (short)f2bf(w1.y);
      f[6] = (short)f2bf(w1.z); f[7] = (short)f2bf(w1.w);
      bfrag[ti][s] = f;
    }
  }
  #pragma unroll
  for (int tt = 0; tt < 2; tt++) {
    int tile = w * 2 + tt;
    const float* dr = data + ((size_t)b * NNODE + tile * 16 + lm) * WINW + kb;
    f32x4 acc[4];
    #pragma unroll
    for (int ti = 0; ti < 4; ti++) acc[ti] = (f32x4){0.f, 0.f, 0.f, 0.f};
    #pragma unroll
    for (int s = 0; s < 2; s++) {
      float4 d0 = *(const float4*)(dr + s * 32);
      float4 d1 = *(const float4*)(dr + s * 32 + 4);
      bf16x8 af;
      af[0] = (short)f2bf(d0.x); af[1] = (short)f2bf(d0.y);
      af[2] = (short)f2bf(d0.z); af[3] = (short)f2bf(d0.w);
      af[4] = (short)f2bf(d1.x); af[5] = (short)f2bf(d1.y);
      af[6] = (short)f2bf(d1.z); af[7] = (short)f2bf(d1.w);
      #pragma unroll
      for (int ti = 0; ti < 4; ti++)
        acc[ti] = __builtin_amdgcn_mfma_f32_16x16x32_bf16(af, bfrag[ti][s], acc[ti], 0, 0, 0);
    }
    #pragma unroll
    for (int r = 0; r < 4; r++) {
      int nd = tile * 16 + lq * 4 + r;
      float si = 0.f, sj = 0.f;
      #pragma unroll
      for (int ti = 0; ti < 4; ti++) {
        float v = acc[ti][r];
        xl[nd * EMBD + ti * 16 + lm] = v;
        si += v * ai4[ti];
        sj += v * aj4[ti];
      }
      si += __shfl_xor(si, 1); si += __shfl_xor(si, 2);
      si += __shfl_xor(si, 4); si += __shfl_xor(si, 8);
      sj += __shfl_xor(sj, 1); sj += __shfl_xor(sj, 2);
      sj += __shfl_xor(sj, 4); sj += __shfl_xor(sj, 8);
      if (lm == 0) { ssi[nd] = si + emb_si[nd]; ssj[nd] = sj + emb_sj[nd]; }
    }
  }
  __syncthreads();
  const int nd4 = ln >> 4, l4 = ln & 15;
  float psx = 0.f, psy = 0.f, psz = 0.f, psw = 0.f;
  float qsx = 0.f, qsy = 0.f, qsz = 0.f, qsw = 0.f;
  for (int it = 0; it < 8; it++) {
    int node = w * 32 + it * 4 + nd4;
    const int4* tp = (const int4*)(topk + node * KTOP);
    int4 i0 = tp[0], i1 = tp[1], i2 = tp[2], i3 = tp[3];
    int idx[16] = {i0.x, i0.y, i0.z, i0.w, i1.x, i1.y, i1.z, i1.w,
                   i2.x, i2.y, i2.z, i2.w, i3.x, i3.y, i3.z, i3.w};
    float sid = ssi[node];
    float al[16], mx = -1e30f;
    #pragma unroll
    for (int k = 0; k < KTOP; k++) {
      float a = sid + ssj[idx[k]];
      a = a > 0.f ? a : NEGS * a;
      al[k] = a;
      mx = fmaxf(mx, a);
    }
    float den = 0.f;
    #pragma unroll
    for (int k = 0; k < KTOP; k++) { al[k] = __expf(al[k] - mx); den += al[k]; }
    float inv = 1.f / den;
    float ax = 0.f, ay = 0.f, az = 0.f, aw = 0.f;
    #pragma unroll
    for (int k = 0; k < KTOP; k++) {
      float4 v = *(const float4*)&xl[idx[k] * EMBD + l4 * 4];
      ax += al[k] * v.x; ay += al[k] * v.y; az += al[k] * v.z; aw += al[k] * v.w;
    }
    ax *= inv; ay *= inv; az *= inv; aw *= inv;
    float4 st = {ax, ay, az, aw};
    *(float4*)(agg + ((size_t)b * NNODE + node) * EMBD + l4 * 4) = st;
    psx += ax; psy += ay; psz += az; psw += aw;
    qsx += ax * ax; qsy += ay * ay; qsz += az * az; qsw += aw * aw;
  }
  #pragma unroll
  for (int o = 16; o <= 32; o <<= 1) {
    psx += __shfl_xor(psx, o); psy += __shfl_xor(psy, o);
    psz += __shfl_xor(psz, o); psw += __shfl_xor(psw, o);
    qsx += __shfl_xor(qsx, o); qsy += __shfl_xor(qsy, o);
    qsz += __shfl_xor(qsz, o); qsw += __shfl_xor(qsw, o);
  }
  if (ln < 16) {
    float4 a = {psx, psy, psz, psw};
    float4 q = {qsx, qsy, qsz, qsw};
    *(float4*)&redb[w * 128 + ln * 4] = a;
    *(float4*)&redb[w * 128 + 64 + ln * 4] = q;
  }
  __syncthreads();
  if (t < 64) {
    float s = 0.f;
    #pragma unroll
    for (int w16 = 0; w16 < 16; w16++) s += redb[w16 * 128 + t];
    atomicAdd(&gsum1[t], s);
  } else if (t < 128) {
    int e = t - 64;
    float s = 0.f;
    #pragma unroll
    for (int w16 = 0; w16 < 16; w16++) s += redb[w16 * 128 + 64 + e];
    atomicAdd(&gss1[e], s);
  }
}

// ---- finalize BN coefficients: a = g*rsqrt(var+eps), c = b - mean*a --------
__global__ void k_fin(const float* __restrict__ gsum, const float* __restrict__ gss,
                      const float* __restrict__ g, const float* __restrict__ bb,
                      float* __restrict__ a, float* __restrict__ c, int C) {
  int e = blockIdx.x * blockDim.x + threadIdx.x;
  if (e >= C) return;
  const float invn = 1.f / (float)NTOT;
  float m = gsum[e] * invn;
  float v = gss[e] * invn - m * m;
  float aa = g[e] * rsqrtf(v + EPSBN);
  a[e] = aa;
  c[e] = bb[e] - m * aa;
}

// ---- K5: z = relu(bn1(agg))*W_emb -> z_bf16 (packed pairs) + BN2 stats -----
__global__ __launch_bounds__(256) void k_zstats2(
    const float* __restrict__ agg, const float* __restrict__ W_emb,
    const float* __restrict__ a1, const float* __restrict__ c1,
    unsigned* __restrict__ zp, float* __restrict__ gsum2,
    float* __restrict__ gss2) {
  __shared__ float red[4][8][32];
  int t = threadIdx.x;
  int gid = blockIdx.x * 256 + t;
  int p = t & 31;                  // channel pair id, fixed across iters
  int c0 = 2 * p;
  float a10 = a1[c0], a11 = a1[c0 + 1], c10 = c1[c0], c11 = c1[c0 + 1];
  const float2* agg2 = (const float2*)agg;
  const float2* we2  = (const float2*)W_emb;
  float ps0 = 0.f, ps1 = 0.f, q0 = 0.f, q1 = 0.f;
  int stride = gridDim.x * 256;
  for (int idx = gid; idx < NTOT * 32; idx += stride) {
    float2 v = agg2[idx];
    int node = (idx >> 5) & (NNODE - 1);
    float2 w = we2[node * 32 + p];
    float z0 = v.x * a10 + c10; z0 = z0 > 0.f ? z0 : 0.f; z0 *= w.x;
    float z1 = v.y * a11 + c11; z1 = z1 > 0.f ? z1 : 0.f; z1 *= w.y;
    zp[idx] = (unsigned)f2bf(z0) | ((unsigned)f2bf(z1) << 16);
    ps0 += z0; q0 += z0 * z0; ps1 += z1; q1 += z1 * z1;
  }
  int g = t >> 5;
  red[0][g][p] = ps0; red[1][g][p] = ps1; red[2][g][p] = q0; red[3][g][p] = q1;
  __syncthreads();
  if (t < 128) {
    int v = t >> 5, p2 = t & 31;
    float s = 0.f;
    #pragma unroll
    for (int k = 0; k < 8; k++) s += red[v][k][p2];
    float* dst = (v & 2) ? gss2 : gsum2;
    atomicAdd(&dst[2 * p2 + (v & 1)], s);
  }
}

// ---- K6: Gram G = h^T h (64x64) + column sums of h, h = relu(bn2(z)) -------
// 512 blocks x 256 thr; per-wave private 8x8-blocked G in regs; per-block
// partials to global; rows disjoint per wave.
__global__ __launch_bounds__(256) void k_gram(
    const unsigned* __restrict__ zp, const float* __restrict__ a2,
    const float* __restrict__ c2, float* __restrict__ Gpart,
    float* __restrict__ hpart) {
  __shared__ float hst[128 * 68];   // 128 rows, pitch 68 words (272 B)
  __shared__ float red[4][64];
  const int t = threadIdx.x, wv = t >> 6, ln = t & 63;
  const int i0 = 8 * (ln & 7), j0 = 8 * (ln >> 3);
  const int p = t & 31, c0 = 2 * p;
  float a20 = a2[c0], a21 = a2[c0 + 1], c20 = c2[c0], c21 = c2[c0 + 1];
  float ga[8][8];
  #pragma unroll
  for (int a = 0; a < 8; a++)
    #pragma unroll
    for (int b = 0; b < 8; b++) ga[a][b] = 0.f;
  float hs[8] = {0.f, 0.f, 0.f, 0.f, 0.f, 0.f, 0.f, 0.f};
  const int rowbase = blockIdx.x * 256;
  for (int st = 0; st < 2; st++) {
    int base32 = (rowbase + st * 128) * 32;
    unsigned us[16];
    #pragma unroll
    for (int s = 0; s < 16; s++) us[s] = zp[base32 + s * 256 + t];
    __syncthreads();
    #pragma unroll
    for (int s = 0; s < 16; s++) {
      int row = s * 8 + (t >> 5);
      float z0 = bf2f(us[s] & 0xffffu);
      float z1 = bf2f(us[s] >> 16);
      float h0 = z0 * a20 + c20; h0 = h0 > 0.f ? h0 : 0.f;
      float h1 = z1 * a21 + c21; h1 = h1 > 0.f ? h1 : 0.f;
      *(float2*)&hst[row * 68 + c0] = make_float2(h0, h1);
    }
    __syncthreads();
    for (int q = 0; q < 32; q++) {
      int r = wv * 32 + q;
      float4 hi0 = *(const float4*)&hst[r * 68 + i0];
      float4 hi1 = *(const float4*)&hst[r * 68 + i0 + 4];
      float4 hj0 = *(const float4*)&hst[r * 68 + j0];
      float4 hj1 = *(const float4*)&hst[r * 68 + j0 + 4];
      float hia[8] = {hi0.x, hi0.y, hi0.z, hi0.w, hi1.x, hi1.y, hi1.z, hi1.w};
      float hja[8] = {hj0.x, hj0.y, hj0.z, hj0.w, hj1.x, hj1.y, hj1.z, hj1.w};
      #pragma unroll
      for (int a = 0; a < 8; a++) {
        float hv = hia[a];
        hs[a] += hv;
        #pragma unroll
        for (int b = 0; b < 8; b++) ga[a][b] += hv * hja[b];
      }
    }
  }
  // ---- block-level G reduction in LDS (reuse hst) ----
  __syncthreads();
  float* G_lds = hst;
  for (int k = t; k < 4096; k += 256) G_lds[k] = 0.f;
  __syncthreads();
  for (int w = 0; w < 4; w++) {
    if (wv == w) {
      #pragma unroll
      for (int a = 0; a < 8; a++)
        #pragma unroll
        for (int bb = 0; bb < 8; bb++) {
          int b = (bb + (ln & 7)) & 7;   // stagger -> 2-way banks only
          G_lds[(i0 + a) * 64 + j0 + b] += ga[a][b];
        }
    }
    __syncthreads();
  }
  for (int k = t; k < 4096; k += 256) Gpart[(size_t)blockIdx.x * 4096 + k] = G_lds[k];
  // ---- hsum: each i-seg duplicated 8x across j-groups -> /8 after reduce ----
  #pragma unroll
  for (int k = 0; k < 8; k++) {
    float v = hs[k];
    v += __shfl_xor(v, 8); v += __shfl_xor(v, 16); v += __shfl_xor(v, 32);
    hs[k] = v * 0.125f;
  }
  if (ln < 8) {
    #pragma unroll
    for (int k = 0; k < 8; k++) red[wv][ln * 8 + k] = hs[k];
  }
  __syncthreads();
  if (t < 64)
    hpart[(size_t)blockIdx.x * 64 + t] = red[0][t] + red[1][t] + red[2][t] + red[3][t];
}

// ---- K6b: reduce Gpart/hpart (atomicAdd into zeroed G/hsum) ----------------
__global__ __launch_bounds__(256) void k_gred(const float* __restrict__ Gpart,
                                              const float* __restrict__ hpart,
                                              float* __restrict__ G,
                                              float* __restrict__ hsum) {
  int wi = blockIdx.x * 256 + threadIdx.x;   // grid 130*256 = 33280
  if (wi < 32768) {
    int e = wi & 4095, seg = wi >> 12;       // 8 segments of 64 blocks
    float s = 0.f;
    #pragma unroll 8
    for (int k = 0; k < 64; k++) s += Gpart[(size_t)((seg << 6) + k) * 4096 + e];
    atomicAdd(&G[e], s);
  } else {
    int wi2 = wi - 32768;                    // < 512
    int e = wi2 & 63, seg = wi2 >> 6;
    float s = 0.f;
    #pragma unroll 8
    for (int k = 0; k < 64; k++) s += hpart[(size_t)((seg << 6) + k) * 64 + e];
    atomicAdd(&hsum[e], s);
  }
}

// ---- K6c: BN3 coefs from Gram: per channel c quadform W1c^T G W1c ----------
__global__ __launch_bounds__(64) void k_fin3q(
    const float* __restrict__ G, const float* __restrict__ hsum,
    const float* __restrict__ W1, const float* __restrict__ b1,
    const float* __restrict__ g3, const float* __restrict__ b3,
    float* __restrict__ a3, float* __restrict__ c3) {
  __shared__ float sw[64];
  int c = blockIdx.x, i = threadIdx.x;
  float w1i = W1[c * 64 + i];
  sw[i] = w1i;
  __syncthreads();
  float gw = 0.f;
  #pragma unroll
  for (int j = 0; j < 64; j++) gw += G[j * 64 + i] * sw[j];   // G symmetric -> coalesced
  float t1 = w1i * gw;       // -> quadform
  float t2 = w1i * hsum[i];  // -> sum of dots
  for (int o = 32; o > 0; o >>= 1) { t1 += __shfl_xor(t1, o); t2 += __shfl_xor(t2, o); }
  if (i == 0) {
    float b1c = b1[c];
    const float fn = (float)NTOT, invn = 1.f / fn;
    float sum3 = t2 + fn * b1c;
    float ss3  = t1 + 2.f * b1c * t2 + fn * b1c * b1c;
    float m = sum3 * invn;
    float v = ss3 * invn - m * m;
    float aa = g3[c] * rsqrtf(v + EPSBN);
    a3[c] = aa;
    c3[c] = b3[c] - m * aa;
  }
}

// ---- K7: output GEMM: h (LDS-staged, swizzled) x W1^T (reg B-frags),
//          fused BN3+relu+W2 dot -> out. 256 blocks x 512 thr (8 waves). -----
__global__ __launch_bounds__(512) void k_gout2(
    const unsigned* __restrict__ zpu, const float* __restrict__ W1,
    const float* __restrict__ b1, const float* __restrict__ a2,
    const float* __restrict__ c2, const float* __restrict__ a3,
    const float* __restrict__ c3, const float* __restrict__ W2,
    const float* __restrict__ b2, float* __restrict__ out) {
  __shared__ uint4 hstage[64 * 8];     // 8 KB: 64 rows x 8 swizzled 16B groups
  __shared__ float opart[64][9];
  const int t = threadIdx.x, wv = t >> 6, ln = t & 63;
  const int lm = ln & 15, lq = ln >> 4, kb = lq * 8;
  const int srow = t >> 3, sg = t & 7;
  const uint4* zp4 = (const uint4*)zpu;

  float a2v[8], c2v[8];
  #pragma unroll
  for (int j = 0; j < 8; j++) { a2v[j] = a2[sg * 8 + j]; c2v[j] = c2[sg * 8 + j]; }

  bf16x8 bfrag[4][2];
  float b1c[4], a3c[4], c3c[4], w2c[4];
  #pragma unroll
  for (int nt = 0; nt < 4; nt++) {
    int col = wv * 64 + nt * 16 + lm;
    b1c[nt] = b1[col]; a3c[nt] = a3[col]; c3c[nt] = c3[col]; w2c[nt] = W2[col];
    #pragma unroll
    for (int s = 0; s < 2; s++) {
      const float* wp = W1 + col * EMBD + s * 32 + kb;
      float4 w0 = *(const float4*)wp;
      float4 w1 = *(const float4*)(wp + 4);
      bf16x8 f;
      f[0] = (short)f2bf(w0.x); f[1] = (short)f2bf(w0.y);
      f[2] = (short)f2bf(w0.z); f[3] = (short)f2bf(w0.w);
      f[4] = (short)f2bf(w1.x); f[5] = (short)f2bf(w1.y);
      f[6] = (short)f2bf(w1.z); f[7] = (short)f2bf(w1.w);
      bfrag[nt][s] = f;
    }
  }
  float b2v = b2[0];
  const int rowbase = blockIdx.x * 512;
  for (int st = 0; st < 8; st++) {
    int base = rowbase + st * 64;
    // prefetch + bn2 + pack (before barrier)
    uint4 u = zp4[(size_t)(base + srow) * 8 + sg];
    float v[8] = {bf2f(u.x & 0xffffu), bf2f(u.x >> 16),
                  bf2f(u.y & 0xffffu), bf2f(u.y >> 16),
                  bf2f(u.z & 0xffffu), bf2f(u.z >> 16),
                  bf2f(u.w & 0xffffu), bf2f(u.w >> 16)};
    unsigned hp[4];
    #pragma unroll
    for (int j = 0; j < 4; j++) {
      float h0 = v[2 * j] * a2v[2 * j] + c2v[2 * j];     h0 = h0 > 0.f ? h0 : 0.f;
      float h1 = v[2 * j + 1] * a2v[2 * j + 1] + c2v[2 * j + 1]; h1 = h1 > 0.f ? h1 : 0.f;
      hp[j] = (unsigned)f2bf(h0) | ((unsigned)f2bf(h1) << 16);
    }
    __syncthreads();   // prior stage fully consumed
    hstage[srow * 8 + (sg ^ (srow & 7))] = make_uint4(hp[0], hp[1], hp[2], hp[3]);
    __syncthreads();
    f32x4 acc[4][4];
    #pragma unroll
    for (int mt = 0; mt < 4; mt++)
      #pragma unroll
      for (int nt = 0; nt < 4; nt++) acc[mt][nt] = (f32x4){0.f, 0.f, 0.f, 0.f};
    const bf16x8* hb = (const bf16x8*)hstage;
    #pragma unroll
    for (int s = 0; s < 2; s++) {
      bf16x8 af[4];
      #pragma unroll
      for (int mt = 0; mt < 4; mt++) {
        int row = mt * 16 + lm;
        af[mt] = hb[row * 8 + ((s * 4 + lq) ^ (row & 7))];
      }
      #pragma unroll
      for (int mt = 0; mt < 4; mt++)
        #pragma unroll
        for (int nt = 0; nt < 4; nt++)
          acc[mt][nt] = __builtin_amdgcn_mfma_f32_16x16x32_bf16(af[mt], bfrag[nt][s], acc[mt][nt], 0, 0, 0);
    }
    #pragma unroll
    for (int mt = 0; mt < 4; mt++) {
      #pragma unroll
      for (int r = 0; r < 4; r++) {
        float p = 0.f;
        #pragma unroll
        for (int nt = 0; nt < 4; nt++) {
          float z2 = acc[mt][nt][r] + b1c[nt];
          float y = z2 * a3c[nt] + c3c[nt];
          y = y > 0.f ? y : 0.f;
          p += y * w2c[nt];
        }
        p += __shfl_xor(p, 1); p += __shfl_xor(p, 2);
        p += __shfl_xor(p, 4); p += __shfl_xor(p, 8);
        if (lm == 0) opart[mt * 16 + lq * 4 + r][wv] = p;
      }
    }
    __syncthreads();
    if (t < 64) {
      float s = 0.f;
      #pragma unroll
      for (int w = 0; w < 8; w++) s += opart[t][w];
      out[base + t] = s + b2v;
    }
  }
}

extern "C" void kernel_launch(void* const* d_in, const int* in_sizes, int n_in,
                              void* d_out, int out_size, void* d_ws, size_t ws_size,
                              hipStream_t stream) {
  const float* data     = (const float*)d_in[0];
  // d_in[1] org_edge_index: unused by forward
  const float* W_emb    = (const float*)d_in[2];
  const float* W_lin    = (const float*)d_in[3];
  const float* att_i    = (const float*)d_in[4];
  const float* att_j    = (const float*)d_in[5];
  const float* att_em_i = (const float*)d_in[6];
  const float* att_em_j = (const float*)d_in[7];
  // d_in[8] b_gnn: cancels exactly inside training-mode BN1
  const float* g_bn1    = (const float*)d_in[9];
  const float* b_bn1    = (const float*)d_in[10];
  const float* g_bn2    = (const float*)d_in[11];
  const float* b_bn2    = (const float*)d_in[12];
  const float* W1       = (const float*)d_in[13];
  const float* b1       = (const float*)d_in[14];
  const float* g_bn3    = (const float*)d_in[15];
  const float* b_bn3    = (const float*)d_in[16];
  const float* W2       = (const float*)d_in[17];
  const float* b2       = (const float*)d_in[18];
  float* out = (float*)d_out;

  char* p = (char*)d_ws;
  auto alloc = [&](size_t bytes) {
    void* r = (void*)p;
    p += (bytes + 255) & ~(size_t)255;
    return r;
  };
  float*    agg   = (float*)alloc((size_t)NTOT * EMBD * 4);      // 33.5 MB
  unsigned* zb    = (unsigned*)alloc((size_t)NTOT * EMBD * 2);   // 16.8 MB bf16
  float*    Gpart = (float*)alloc((size_t)512 * 4096 * 4);       // 8.4 MB
  float*    hpart = (float*)alloc((size_t)512 * 64 * 4);
  float*    nw    = (float*)alloc((size_t)NNODE * EMBD * 4);
  float*    emb_si = (float*)alloc(NNODE * 4);
  float*    emb_sj = (float*)alloc(NNODE * 4);
  int*      topk   = (int*)alloc(NNODE * KTOP * 4);
  float*    stats  = (float*)alloc(4416 * 4);   // gsum1,gss1,gsum2,gss2,G,hsum
  float*    coefs  = (float*)alloc(1280 * 4);   // a1,c1,a2,c2,a3,c3

  float* gsum1 = stats;       float* gss1 = stats + 64;
  float* gsum2 = stats + 128; float* gss2 = stats + 192;
  float* G     = stats + 256; float* hsum = stats + 4352;
  float* a1 = coefs;       float* c1 = coefs + 64;
  float* a2 = coefs + 128; float* c2 = coefs + 192;
  float* a3 = coefs + 256; float* c3 = coefs + 768;

  hipMemsetAsync(stats, 0, 4416 * 4, stream);

  k_prep<<<NNODE, 64, 0, stream>>>(W_emb, att_em_i, att_em_j, nw, emb_si, emb_sj);
  k_topk<<<NNODE, 256, 0, stream>>>(nw, topk);
  k_fuse<<<BATCH, 1024, 0, stream>>>(data, W_lin, att_i, att_j, emb_si, emb_sj,
                                     topk, agg, gsum1, gss1);
  k_fin<<<1, 64, 0, stream>>>(gsum1, gss1, g_bn1, b_bn1, a1, c1, EMBD);
  k_zstats2<<<1024, 256, 0, stream>>>(agg, W_emb, a1, c1, zb, gsum2, gss2);
  k_fin<<<1, 64, 0, stream>>>(gsum2, gss2, g_bn2, b_bn2, a2, c2, EMBD);
  k_gram<<<512, 256, 0, stream>>>(zb, a2, c2, Gpart, hpart);
  k_gred<<<130, 256, 0, stream>>>(Gpart, hpart, G, hsum);
  k_fin3q<<<CIN, 64, 0, stream>>>(G, hsum, W1, b1, g_bn3, b_bn3, a3, c3);
  k_gout2<<<256, 512, 0, stream>>>(zb, W1, b1, a2, c2, a3, c3, W2, b2, out);
}

// Round 5
// 283.038 us; speedup vs baseline: 3.0380x; 1.0083x over previous
//
#include <hip/hip_runtime.h>
#include <hip/hip_bf16.h>

constexpr int BATCH = 256, NNODE = 512, WINW = 64, EMBD = 64, KTOP = 16, CIN = 512;
constexpr int NTOT = BATCH * NNODE;          // 131072
constexpr float NEGS = 0.2f;
constexpr float EPSBN = 1e-5f;

typedef __attribute__((ext_vector_type(8))) short bf16x8;
typedef __attribute__((ext_vector_type(4))) float f32x4;

union U8 { uint4 u; bf16x8 b; };

__device__ inline float bf2f(unsigned u16) {
  union { unsigned u; float f; } v; v.u = u16 << 16; return v.f;
}
__device__ inline unsigned short f2bf(float x) {
  union { float f; unsigned u; } v; v.f = x;
  unsigned r = v.u + 0x7fff + ((v.u >> 16) & 1);   // RNE
  return (unsigned short)(r >> 16);
}

// ---- K0: normalize embeddings + per-node attention-embedding dots ----------
__global__ void k_prep(const float* __restrict__ W_emb,
                       const float* __restrict__ att_em_i,
                       const float* __restrict__ att_em_j,
                       float* __restrict__ nw, float* __restrict__ emb_si,
                       float* __restrict__ emb_sj) {
  int i = blockIdx.x, e = threadIdx.x;   // block = 64 threads
  float w  = W_emb[i * EMBD + e];
  float sq = w * w;
  float si = w * att_em_i[e];
  float sj = w * att_em_j[e];
  for (int o = 32; o > 0; o >>= 1) {
    sq += __shfl_xor(sq, o);
    si += __shfl_xor(si, o);
    sj += __shfl_xor(sj, o);
  }
  nw[i * EMBD + e] = w * rsqrtf(sq);
  if (e == 0) { emb_si[i] = si; emb_sj[i] = sj; }
}

// ---- K1: cosine top-16 per node — shuffle argmax ---------------------------
__global__ __launch_bounds__(256) void k_topk(const float* __restrict__ nw,
                                              int* __restrict__ topk) {
  __shared__ float nwi[EMBD];
  __shared__ float wbv[4];
  __shared__ int   wbi[4];
  __shared__ int   winner;
  int i = blockIdx.x, t = threadIdx.x, wv = t >> 6, ln = t & 63;
  if (t < EMBD) nwi[t] = nw[i * EMBD + t];
  __syncthreads();
  float v0 = 0.f, v1 = 0.f;
  #pragma unroll
  for (int k = 0; k < EMBD; k++) {
    v0 += nw[t * EMBD + k] * nwi[k];
    v1 += nw[(t + 256) * EMBD + k] * nwi[k];
  }
  for (int sel = 0; sel < KTOP; sel++) {
    float bv; int bi;
    if (v1 > v0) { bv = v1; bi = t + 256; } else { bv = v0; bi = t; }  // tie -> lower idx
    #pragma unroll
    for (int o = 1; o < 64; o <<= 1) {
      float ov = __shfl_xor(bv, o);
      int   oi = __shfl_xor(bi, o);
      if (ov > bv || (ov == bv && oi < bi)) { bv = ov; bi = oi; }
    }
    if (ln == 0) { wbv[wv] = bv; wbi[wv] = bi; }
    __syncthreads();
    if (t == 0) {
      float B = wbv[0]; int I = wbi[0];
      #pragma unroll
      for (int w = 1; w < 4; w++)
        if (wbv[w] > B || (wbv[w] == B && wbi[w] < I)) { B = wbv[w]; I = wbi[w]; }
      topk[i * KTOP + sel] = I;
      winner = I;
    }
    __syncthreads();
    int wi = winner;
    if (wi == t) v0 = -3.f;
    else if (wi == t + 256) v1 = -3.f;
  }
}

// ============================================================================
// K_FUSE: one block per batch (grid=256, 1024 thr = 16 waves).
// Phase A: xl = x @ W_lin^T via bf16 MFMA -> LDS; Phase B: softmax+agg.
// agg stored as packed bf16 pairs; BN1 stats accumulated in fp32.
// ============================================================================
__global__ __launch_bounds__(1024) void k_fuse(
    const float* __restrict__ data, const float* __restrict__ W_lin,
    const float* __restrict__ att_i, const float* __restrict__ att_j,
    const float* __restrict__ emb_si, const float* __restrict__ emb_sj,
    const int* __restrict__ topk,
    unsigned* __restrict__ aggb, float* __restrict__ gsum1,
    float* __restrict__ gss1) {
  __shared__ float xl[NNODE * EMBD];      // 128 KB
  __shared__ float ssi[NNODE];
  __shared__ float ssj[NNODE];
  __shared__ float redb[16 * 128];
  const int b = blockIdx.x;
  const int t = threadIdx.x, w = t >> 6, ln = t & 63;
  const int lm = ln & 15, lq = ln >> 4, kb = lq * 8;

  bf16x8 bfrag[4][2];
  float ai4[4], aj4[4];
  #pragma unroll
  for (int ti = 0; ti < 4; ti++) {
    int ch = ti * 16 + lm;
    ai4[ti] = att_i[ch]; aj4[ti] = att_j[ch];
    #pragma unroll
    for (int s = 0; s < 2; s++) {
      const float* wp = W_lin + ch * WINW + s * 32 + kb;
      float4 w0 = *(const float4*)wp;
      float4 w1 = *(const float4*)(wp + 4);
      bf16x8 f;
      f[0] = (short)f2bf(w0.x); f[1] = (short)f2bf(w0.y);
      f[2] = (short)f2bf(w0.z); f[3] = (short)f2bf(w0.w);
      f[4] = (short)f2bf(w1.x); f[5] = (short)f2bf(w1.y);
      f[6] = (short)f2bf(w1.z); f[7] = (short)f2bf(w1.w);
      bfrag[ti][s] = f;
    }
  }
  #pragma unroll
  for (int tt = 0; tt < 2; tt++) {
    int tile = w * 2 + tt;
    const float* dr = data + ((size_t)b * NNODE + tile * 16 + lm) * WINW + kb;
    f32x4 acc[4];
    #pragma unroll
    for (int ti = 0; ti < 4; ti++) acc[ti] = (f32x4){0.f, 0.f, 0.f, 0.f};
    #pragma unroll
    for (int s = 0; s < 2; s++) {
      float4 d0 = *(const float4*)(dr + s * 32);
      float4 d1 = *(const float4*)(dr + s * 32 + 4);
      bf16x8 af;
      af[0] = (short)f2bf(d0.x); af[1] = (short)f2bf(d0.y);
      af[2] = (short)f2bf(d0.z); af[3] = (short)f2bf(d0.w);
      af[4] = (short)f2bf(d1.x); af[5] = (short)f2bf(d1.y);
      af[6] = (short)f2bf(d1.z); af[7] = (short)f2bf(d1.w);
      #pragma unroll
      for (int ti = 0; ti < 4; ti++)
        acc[ti] = __builtin_amdgcn_mfma_f32_16x16x32_bf16(af, bfrag[ti][s], acc[ti], 0, 0, 0);
    }
    #pragma unroll
    for (int r = 0; r < 4; r++) {
      int nd = tile * 16 + lq * 4 + r;
      float si = 0.f, sj = 0.f;
      #pragma unroll
      for (int ti = 0; ti < 4; ti++) {
        float v = acc[ti][r];
        xl[nd * EMBD + ti * 16 + lm] = v;
        si += v * ai4[ti];
        sj += v * aj4[ti];
      }
      si += __shfl_xor(si, 1); si += __shfl_xor(si, 2);
      si += __shfl_xor(si, 4); si += __shfl_xor(si, 8);
      sj += __shfl_xor(sj, 1); sj += __shfl_xor(sj, 2);
      sj += __shfl_xor(sj, 4); sj += __shfl_xor(sj, 8);
      if (lm == 0) { ssi[nd] = si + emb_si[nd]; ssj[nd] = sj + emb_sj[nd]; }
    }
  }
  __syncthreads();
  const int nd4 = ln >> 4, l4 = ln & 15;
  float psx = 0.f, psy = 0.f, psz = 0.f, psw = 0.f;
  float qsx = 0.f, qsy = 0.f, qsz = 0.f, qsw = 0.f;
  for (int it = 0; it < 8; it++) {
    int node = w * 32 + it * 4 + nd4;
    const int4* tp = (const int4*)(topk + node * KTOP);
    int4 i0 = tp[0], i1 = tp[1], i2 = tp[2], i3 = tp[3];
    int idx[16] = {i0.x, i0.y, i0.z, i0.w, i1.x, i1.y, i1.z, i1.w,
                   i2.x, i2.y, i2.z, i2.w, i3.x, i3.y, i3.z, i3.w};
    float sid = ssi[node];
    float al[16], mx = -1e30f;
    #pragma unroll
    for (int k = 0; k < KTOP; k++) {
      float a = sid + ssj[idx[k]];
      a = a > 0.f ? a : NEGS * a;
      al[k] = a;
      mx = fmaxf(mx, a);
    }
    float den = 0.f;
    #pragma unroll
    for (int k = 0; k < KTOP; k++) { al[k] = __expf(al[k] - mx); den += al[k]; }
    float inv = 1.f / den;
    float ax = 0.f, ay = 0.f, az = 0.f, aw = 0.f;
    #pragma unroll
    for (int k = 0; k < KTOP; k++) {
      float4 v = *(const float4*)&xl[idx[k] * EMBD + l4 * 4];
      ax += al[k] * v.x; ay += al[k] * v.y; az += al[k] * v.z; aw += al[k] * v.w;
    }
    ax *= inv; ay *= inv; az *= inv; aw *= inv;
    unsigned u0 = (unsigned)f2bf(ax) | ((unsigned)f2bf(ay) << 16);
    unsigned u1 = (unsigned)f2bf(az) | ((unsigned)f2bf(aw) << 16);
    *(uint2*)(aggb + (((size_t)b * NNODE + node) << 5) + l4 * 2) = make_uint2(u0, u1);
    psx += ax; psy += ay; psz += az; psw += aw;
    qsx += ax * ax; qsy += ay * ay; qsz += az * az; qsw += aw * aw;
  }
  #pragma unroll
  for (int o = 16; o <= 32; o <<= 1) {
    psx += __shfl_xor(psx, o); psy += __shfl_xor(psy, o);
    psz += __shfl_xor(psz, o); psw += __shfl_xor(psw, o);
    qsx += __shfl_xor(qsx, o); qsy += __shfl_xor(qsy, o);
    qsz += __shfl_xor(qsz, o); qsw += __shfl_xor(qsw, o);
  }
  if (ln < 16) {
    float4 a = {psx, psy, psz, psw};
    float4 q = {qsx, qsy, qsz, qsw};
    *(float4*)&redb[w * 128 + ln * 4] = a;
    *(float4*)&redb[w * 128 + 64 + ln * 4] = q;
  }
  __syncthreads();
  if (t < 64) {
    float s = 0.f;
    #pragma unroll
    for (int w16 = 0; w16 < 16; w16++) s += redb[w16 * 128 + t];
    atomicAdd(&gsum1[t], s);
  } else if (t < 128) {
    int e = t - 64;
    float s = 0.f;
    #pragma unroll
    for (int w16 = 0; w16 < 16; w16++) s += redb[w16 * 128 + 64 + e];
    atomicAdd(&gss1[e], s);
  }
}

// ---- finalize BN coefficients: a = g*rsqrt(var+eps), c = b - mean*a --------
__global__ void k_fin(const float* __restrict__ gsum, const float* __restrict__ gss,
                      const float* __restrict__ g, const float* __restrict__ bb,
                      float* __restrict__ a, float* __restrict__ c, int C) {
  int e = blockIdx.x * blockDim.x + threadIdx.x;
  if (e >= C) return;
  const float invn = 1.f / (float)NTOT;
  float m = gsum[e] * invn;
  float v = gss[e] * invn - m * m;
  float aa = g[e] * rsqrtf(v + EPSBN);
  a[e] = aa;
  c[e] = bb[e] - m * aa;
}

// ---- K5: z = relu(bn1(agg))*W_emb -> z_bf16 (packed pairs) + BN2 stats -----
__global__ __launch_bounds__(256) void k_zstats2(
    const unsigned* __restrict__ aggb, const float* __restrict__ W_emb,
    const float* __restrict__ a1, const float* __restrict__ c1,
    unsigned* __restrict__ zp, float* __restrict__ gsum2,
    float* __restrict__ gss2) {
  __shared__ float red[4][8][32];
  int t = threadIdx.x;
  int gid = blockIdx.x * 256 + t;
  int p = t & 31;                  // channel pair id, fixed across iters
  int c0 = 2 * p;
  float a10 = a1[c0], a11 = a1[c0 + 1], c10 = c1[c0], c11 = c1[c0 + 1];
  const float2* we2  = (const float2*)W_emb;
  float ps0 = 0.f, ps1 = 0.f, q0 = 0.f, q1 = 0.f;
  int stride = gridDim.x * 256;
  for (int idx = gid; idx < NTOT * 32; idx += stride) {
    unsigned u = aggb[idx];
    float vx = bf2f(u & 0xffffu), vy = bf2f(u >> 16);
    int node = (idx >> 5) & (NNODE - 1);
    float2 w = we2[node * 32 + p];
    float z0 = vx * a10 + c10; z0 = z0 > 0.f ? z0 : 0.f; z0 *= w.x;
    float z1 = vy * a11 + c11; z1 = z1 > 0.f ? z1 : 0.f; z1 *= w.y;
    zp[idx] = (unsigned)f2bf(z0) | ((unsigned)f2bf(z1) << 16);
    ps0 += z0; q0 += z0 * z0; ps1 += z1; q1 += z1 * z1;
  }
  int g = t >> 5;
  red[0][g][p] = ps0; red[1][g][p] = ps1; red[2][g][p] = q0; red[3][g][p] = q1;
  __syncthreads();
  if (t < 128) {
    int v = t >> 5, p2 = t & 31;
    float s = 0.f;
    #pragma unroll
    for (int k = 0; k < 8; k++) s += red[v][k][p2];
    float* dst = (v & 2) ? gss2 : gsum2;
    atomicAdd(&dst[2 * p2 + (v & 1)], s);
  }
}

// ---- K6: Gram G = h^T h (64x64) + column sums + h_bf16 materialization -----
__global__ __launch_bounds__(256) void k_gram(
    const unsigned* __restrict__ zp, const float* __restrict__ a2,
    const float* __restrict__ c2, float* __restrict__ Gpart,
    float* __restrict__ hpart, unsigned* __restrict__ hb) {
  __shared__ float hst[128 * 68];   // 128 rows, pitch 68 words (272 B)
  __shared__ float red[4][64];
  const int t = threadIdx.x, wv = t >> 6, ln = t & 63;
  const int i0 = 8 * (ln & 7), j0 = 8 * (ln >> 3);
  const int p = t & 31, c0 = 2 * p;
  float a20 = a2[c0], a21 = a2[c0 + 1], c20 = c2[c0], c21 = c2[c0 + 1];
  float ga[8][8];
  #pragma unroll
  for (int a = 0; a < 8; a++)
    #pragma unroll
    for (int b = 0; b < 8; b++) ga[a][b] = 0.f;
  float hs[8] = {0.f, 0.f, 0.f, 0.f, 0.f, 0.f, 0.f, 0.f};
  const int rowbase = blockIdx.x * 256;
  for (int st = 0; st < 2; st++) {
    int base32 = (rowbase + st * 128) * 32;
    unsigned us[16];
    #pragma unroll
    for (int s = 0; s < 16; s++) us[s] = zp[base32 + s * 256 + t];
    __syncthreads();
    #pragma unroll
    for (int s = 0; s < 16; s++) {
      int row = s * 8 + (t >> 5);
      float z0 = bf2f(us[s] & 0xffffu);
      float z1 = bf2f(us[s] >> 16);
      float h0 = z0 * a20 + c20; h0 = h0 > 0.f ? h0 : 0.f;
      float h1 = z1 * a21 + c21; h1 = h1 > 0.f ? h1 : 0.f;
      *(float2*)&hst[row * 68 + c0] = make_float2(h0, h1);
      hb[(size_t)(rowbase + st * 128 + row) * 32 + p] =
          (unsigned)f2bf(h0) | ((unsigned)f2bf(h1) << 16);
    }
    __syncthreads();
    for (int q = 0; q < 32; q++) {
      int r = wv * 32 + q;
      float4 hi0 = *(const float4*)&hst[r * 68 + i0];
      float4 hi1 = *(const float4*)&hst[r * 68 + i0 + 4];
      float4 hj0 = *(const float4*)&hst[r * 68 + j0];
      float4 hj1 = *(const float4*)&hst[r * 68 + j0 + 4];
      float hia[8] = {hi0.x, hi0.y, hi0.z, hi0.w, hi1.x, hi1.y, hi1.z, hi1.w};
      float hja[8] = {hj0.x, hj0.y, hj0.z, hj0.w, hj1.x, hj1.y, hj1.z, hj1.w};
      #pragma unroll
      for (int a = 0; a < 8; a++) {
        float hv = hia[a];
        hs[a] += hv;
        #pragma unroll
        for (int b = 0; b < 8; b++) ga[a][b] += hv * hja[b];
      }
    }
  }
  __syncthreads();
  float* G_lds = hst;
  for (int k = t; k < 4096; k += 256) G_lds[k] = 0.f;
  __syncthreads();
  for (int w = 0; w < 4; w++) {
    if (wv == w) {
      #pragma unroll
      for (int a = 0; a < 8; a++)
        #pragma unroll
        for (int bb = 0; bb < 8; bb++) {
          int b = (bb + (ln & 7)) & 7;   // stagger -> 2-way banks only
          G_lds[(i0 + a) * 64 + j0 + b] += ga[a][b];
        }
    }
    __syncthreads();
  }
  for (int k = t; k < 4096; k += 256) Gpart[(size_t)blockIdx.x * 4096 + k] = G_lds[k];
  #pragma unroll
  for (int k = 0; k < 8; k++) {
    float v = hs[k];
    v += __shfl_xor(v, 8); v += __shfl_xor(v, 16); v += __shfl_xor(v, 32);
    hs[k] = v * 0.125f;
  }
  if (ln < 8) {
    #pragma unroll
    for (int k = 0; k < 8; k++) red[wv][ln * 8 + k] = hs[k];
  }
  __syncthreads();
  if (t < 64)
    hpart[(size_t)blockIdx.x * 64 + t] = red[0][t] + red[1][t] + red[2][t] + red[3][t];
}

// ---- K6b: reduce Gpart/hpart (atomicAdd into zeroed G/hsum) ----------------
__global__ __launch_bounds__(256) void k_gred(const float* __restrict__ Gpart,
                                              const float* __restrict__ hpart,
                                              float* __restrict__ G,
                                              float* __restrict__ hsum) {
  int wi = blockIdx.x * 256 + threadIdx.x;   // grid 130*256 = 33280
  if (wi < 32768) {
    int e = wi & 4095, seg = wi >> 12;       // 8 segments of 64 blocks
    float s = 0.f;
    #pragma unroll 8
    for (int k = 0; k < 64; k++) s += Gpart[(size_t)((seg << 6) + k) * 4096 + e];
    atomicAdd(&G[e], s);
  } else {
    int wi2 = wi - 32768;                    // < 512
    int e = wi2 & 63, seg = wi2 >> 6;
    float s = 0.f;
    #pragma unroll 8
    for (int k = 0; k < 64; k++) s += hpart[(size_t)((seg << 6) + k) * 64 + e];
    atomicAdd(&hsum[e], s);
  }
}

// ---- K6c: BN3 coefs from Gram: per channel c quadform W1c^T G W1c ----------
__global__ __launch_bounds__(64) void k_fin3q(
    const float* __restrict__ G, const float* __restrict__ hsum,
    const float* __restrict__ W1, const float* __restrict__ b1,
    const float* __restrict__ g3, const float* __restrict__ b3,
    float* __restrict__ a3, float* __restrict__ c3) {
  __shared__ float sw[64];
  int c = blockIdx.x, i = threadIdx.x;
  float w1i = W1[c * 64 + i];
  sw[i] = w1i;
  __syncthreads();
  float gw = 0.f;
  #pragma unroll
  for (int j = 0; j < 64; j++) gw += G[j * 64 + i] * sw[j];   // G symmetric -> coalesced
  float t1 = w1i * gw;       // -> quadform
  float t2 = w1i * hsum[i];  // -> sum of dots
  for (int o = 32; o > 0; o >>= 1) { t1 += __shfl_xor(t1, o); t2 += __shfl_xor(t2, o); }
  if (i == 0) {
    float b1c = b1[c];
    const float fn = (float)NTOT, invn = 1.f / fn;
    float sum3 = t2 + fn * b1c;
    float ss3  = t1 + 2.f * b1c * t2 + fn * b1c * b1c;
    float m = sum3 * invn;
    float v = ss3 * invn - m * m;
    float aa = g3[c] * rsqrtf(v + EPSBN);
    a3[c] = aa;
    c3[c] = b3[c] - m * aa;
  }
}

// ---- K7: output GEMM — barrier-free, LDS-free. Each wave owns a 64-col
//      slice; A-frags load straight from global (h bf16); partials combine
//      via atomicAdd into pre-zeroed out. 512 blocks x 512 thr. --------------
__global__ __launch_bounds__(512) void k_gout3(
    const unsigned* __restrict__ hb, const float* __restrict__ W1,
    const float* __restrict__ b1, const float* __restrict__ a3,
    const float* __restrict__ c3, const float* __restrict__ W2,
    const float* __restrict__ b2, float* __restrict__ out) {
  const int t = threadIdx.x, wv = t >> 6, ln = t & 63;
  const int lm = ln & 15, lq = ln >> 4, kb = lq * 8;
  bf16x8 bfrag[4][2];
  float b1c[4], a3c[4], c3c[4], w2c[4];
  #pragma unroll
  for (int nt = 0; nt < 4; nt++) {
    int col = wv * 64 + nt * 16 + lm;
    b1c[nt] = b1[col]; a3c[nt] = a3[col]; c3c[nt] = c3[col]; w2c[nt] = W2[col];
    #pragma unroll
    for (int s = 0; s < 2; s++) {
      const float* wp = W1 + col * EMBD + s * 32 + kb;
      float4 w0 = *(const float4*)wp;
      float4 w1 = *(const float4*)(wp + 4);
      bf16x8 f;
      f[0] = (short)f2bf(w0.x); f[1] = (short)f2bf(w0.y);
      f[2] = (short)f2bf(w0.z); f[3] = (short)f2bf(w0.w);
      f[4] = (short)f2bf(w1.x); f[5] = (short)f2bf(w1.y);
      f[6] = (short)f2bf(w1.z); f[7] = (short)f2bf(w1.w);
      bfrag[nt][s] = f;
    }
  }
  float b2v = b2[0];
  const uint4* h4 = (const uint4*)hb;
  for (int tile = blockIdx.x; tile < NTOT / 16; tile += gridDim.x) {
    int rowbase = tile * 16;
    U8 ua, ub;
    ua.u = h4[(size_t)(rowbase + lm) * 8 + lq];       // k-half 0
    ub.u = h4[(size_t)(rowbase + lm) * 8 + 4 + lq];   // k-half 1
    f32x4 acc[4];
    #pragma unroll
    for (int nt = 0; nt < 4; nt++) acc[nt] = (f32x4){0.f, 0.f, 0.f, 0.f};
    #pragma unroll
    for (int nt = 0; nt < 4; nt++)
      acc[nt] = __builtin_amdgcn_mfma_f32_16x16x32_bf16(ua.b, bfrag[nt][0], acc[nt], 0, 0, 0);
    #pragma unroll
    for (int nt = 0; nt < 4; nt++)
      acc[nt] = __builtin_amdgcn_mfma_f32_16x16x32_bf16(ub.b, bfrag[nt][1], acc[nt], 0, 0, 0);
    #pragma unroll
    for (int r = 0; r < 4; r++) {
      float p = 0.f;
      #pragma unroll
      for (int nt = 0; nt < 4; nt++) {
        float z2 = acc[nt][r] + b1c[nt];
        float y = z2 * a3c[nt] + c3c[nt];
        y = y > 0.f ? y : 0.f;
        p += y * w2c[nt];
      }
      p += __shfl_xor(p, 1); p += __shfl_xor(p, 2);
      p += __shfl_xor(p, 4); p += __shfl_xor(p, 8);
      if (lm == 0) {
        if (wv == 0) p += b2v;
        atomicAdd(&out[rowbase + lq * 4 + r], p);
      }
    }
  }
}

extern "C" void kernel_launch(void* const* d_in, const int* in_sizes, int n_in,
                              void* d_out, int out_size, void* d_ws, size_t ws_size,
                              hipStream_t stream) {
  const float* data     = (const float*)d_in[0];
  // d_in[1] org_edge_index: unused by forward
  const float* W_emb    = (const float*)d_in[2];
  const float* W_lin    = (const float*)d_in[3];
  const float* att_i    = (const float*)d_in[4];
  const float* att_j    = (const float*)d_in[5];
  const float* att_em_i = (const float*)d_in[6];
  const float* att_em_j = (const float*)d_in[7];
  // d_in[8] b_gnn: cancels exactly inside training-mode BN1
  const float* g_bn1    = (const float*)d_in[9];
  const float* b_bn1    = (const float*)d_in[10];
  const float* g_bn2    = (const float*)d_in[11];
  const float* b_bn2    = (const float*)d_in[12];
  const float* W1       = (const float*)d_in[13];
  const float* b1       = (const float*)d_in[14];
  const float* g_bn3    = (const float*)d_in[15];
  const float* b_bn3    = (const float*)d_in[16];
  const float* W2       = (const float*)d_in[17];
  const float* b2       = (const float*)d_in[18];
  float* out = (float*)d_out;

  char* p = (char*)d_ws;
  auto alloc = [&](size_t bytes) {
    void* r = (void*)p;
    p += (bytes + 255) & ~(size_t)255;
    return r;
  };
  unsigned* aggb  = (unsigned*)alloc((size_t)NTOT * EMBD * 2);   // 16.8 MB bf16
  unsigned* zb    = (unsigned*)alloc((size_t)NTOT * EMBD * 2);   // 16.8 MB bf16
  unsigned* hb    = (unsigned*)alloc((size_t)NTOT * EMBD * 2);   // 16.8 MB bf16
  float*    Gpart = (float*)alloc((size_t)512 * 4096 * 4);       // 8.4 MB
  float*    hpart = (float*)alloc((size_t)512 * 64 * 4);
  float*    nw    = (float*)alloc((size_t)NNODE * EMBD * 4);
  float*    emb_si = (float*)alloc(NNODE * 4);
  float*    emb_sj = (float*)alloc(NNODE * 4);
  int*      topk   = (int*)alloc(NNODE * KTOP * 4);
  float*    stats  = (float*)alloc(4416 * 4);   // gsum1,gss1,gsum2,gss2,G,hsum
  float*    coefs  = (float*)alloc(1280 * 4);   // a1,c1,a2,c2,a3,c3

  float* gsum1 = stats;       float* gss1 = stats + 64;
  float* gsum2 = stats + 128; float* gss2 = stats + 192;
  float* G     = stats + 256; float* hsum = stats + 4352;
  float* a1 = coefs;       float* c1 = coefs + 64;
  float* a2 = coefs + 128; float* c2 = coefs + 192;
  float* a3 = coefs + 256; float* c3 = coefs + 768;

  hipMemsetAsync(stats, 0, 4416 * 4, stream);
  hipMemsetAsync(out, 0, (size_t)NTOT * 4, stream);

  k_prep<<<NNODE, 64, 0, stream>>>(W_emb, att_em_i, att_em_j, nw, emb_si, emb_sj);
  k_topk<<<NNODE, 256, 0, stream>>>(nw, topk);
  k_fuse<<<BATCH, 1024, 0, stream>>>(data, W_lin, att_i, att_j, emb_si, emb_sj,
                                     topk, aggb, gsum1, gss1);
  k_fin<<<1, 64, 0, stream>>>(gsum1, gss1, g_bn1, b_bn1, a1, c1, EMBD);
  k_zstats2<<<1024, 256, 0, stream>>>(aggb, W_emb, a1, c1, zb, gsum2, gss2);
  k_fin<<<1, 64, 0, stream>>>(gsum2, gss2, g_bn2, b_bn2, a2, c2, EMBD);
  k_gram<<<512, 256, 0, stream>>>(zb, a2, c2, Gpart, hpart, hb);
  k_gred<<<130, 256, 0, stream>>>(Gpart, hpart, G, hsum);
  k_fin3q<<<CIN, 64, 0, stream>>>(G, hsum, W1, b1, g_bn3, b_bn3, a3, c3);
  k_gout3<<<512, 512, 0, stream>>>(hb, W1, b1, a3, c3, W2, b2, out);
}